// Round 5
// baseline (224.231 us; speedup 1.0000x reference)
//
#include <hip/hip_runtime.h>
#include <hip/hip_bf16.h>

#define NB 2
#define NS 512
#define ND 1024
#define NH 8
#define NDK 128
#define NDFF 4096
#define QRLD 128
#define RPAD 64
#define BSROWS 1024           /* B*S */
#define NBH 16                /* B*H */

typedef __bf16 bf16x8 __attribute__((ext_vector_type(8)));
typedef __bf16 bf16x4 __attribute__((ext_vector_type(4)));
typedef float f32x4 __attribute__((ext_vector_type(4)));

#define BM 128
#define BN 128
#define BK 64

__device__ __forceinline__ void gload16(const void* g, void* l) {
    __builtin_amdgcn_global_load_lds(
        (const __attribute__((address_space(1))) void*)g,
        (__attribute__((address_space(3))) void*)l, 16, 0, 0);
}

// ---------------------------------------------------------------------------
// 2-phase double-buffered MFMA GEMM: C[M,N] = A[M,K] @ Bt[N,K]^T.
// 128x128 tile, BK=64, 4 waves. Requires nt = Ksp/BK even and >= 2.
// ---------------------------------------------------------------------------
__global__ __launch_bounds__(256) void gemm128(
    const __bf16* __restrict__ A, const __bf16* __restrict__ Bt,
    float* __restrict__ Cf, __bf16* __restrict__ Cb,
    const float* __restrict__ bias,
    int Ksp, int lda, int ldb, int ldc,
    long sA, long sA2, int zdivA,
    long sB, long sB2, int zdivB,
    long sC, int nsplit, long sPart, int flags)
{
    __shared__ __bf16 As0[BM * BK];
    __shared__ __bf16 As1[BM * BK];
    __shared__ __bf16 Bs0[BN * BK];
    __shared__ __bf16 Bs1[BN * BK];

    const int z = blockIdx.z;
    const int bh = z / nsplit, sp = z - bh * nsplit;
    const long kbase = (long)sp * Ksp;
    A  += (long)(bh / zdivA) * sA + (long)(bh % zdivA) * sA2 + kbase;
    Bt += (long)(bh / zdivB) * sB + (long)(bh % zdivB) * sB2 + kbase;
    const long cbase = (long)bh * sC + (long)sp * sPart;

    const int tM = blockIdx.y * BM, tN = blockIdx.x * BN;
    const int t = threadIdx.x, lane = t & 63, w = t >> 6;
    const int wr = w >> 1, wc = w & 1;
    const int srow = lane >> 3;
    const int scol = (lane & 7) * 8;

    const __bf16* gA = A + (long)(tM + srow) * lda + scol;
    const __bf16* gB = Bt + (long)(tN + srow) * ldb + scol;

    f32x4 acc[4][4];
#pragma unroll
    for (int m = 0; m < 4; ++m)
#pragma unroll
        for (int n = 0; n < 4; ++n)
#pragma unroll
            for (int j = 0; j < 4; ++j) acc[m][n][j] = 0.f;

    const int r16 = lane & 15;
    const int kq = (lane >> 4) * 8;
    const int nt = Ksp / BK;

    auto STAGE = [&](__bf16* as, __bf16* bs, int k0) {
#pragma unroll
        for (int i = 0; i < 4; ++i) {
            const int rr = (w * 4 + i) * 8;   // wave-uniform 8-row chunk base
            gload16(gA + (long)rr * lda + k0, (void*)&as[rr * BK]);
            gload16(gB + (long)rr * ldb + k0, (void*)&bs[rr * BK]);
        }
    };
    auto COMPUTE = [&](const __bf16* as, const __bf16* bs) {
#pragma unroll
        for (int ks = 0; ks < 2; ++ks) {
            bf16x8 af[4], bv[4];
#pragma unroll
            for (int m = 0; m < 4; ++m)
                af[m] = *(const bf16x8*)&as[(wr * 64 + m * 16 + r16) * BK + ks * 32 + kq];
#pragma unroll
            for (int n = 0; n < 4; ++n)
                bv[n] = *(const bf16x8*)&bs[(wc * 64 + n * 16 + r16) * BK + ks * 32 + kq];
#pragma unroll
            for (int m = 0; m < 4; ++m)
#pragma unroll
                for (int n = 0; n < 4; ++n)
                    acc[m][n] = __builtin_amdgcn_mfma_f32_16x16x32_bf16(af[m], bv[n], acc[m][n], 0, 0, 0);
        }
    };

    STAGE(As0, Bs0, 0);
    __syncthreads();
    for (int tt = 0; tt < nt; tt += 2) {
        STAGE(As1, Bs1, (tt + 1) * BK);
        COMPUTE(As0, Bs0);
        __syncthreads();
        if (tt + 2 < nt) STAGE(As0, Bs0, (tt + 2) * BK);
        COMPUTE(As1, Bs1);
        __syncthreads();
    }

    const bool relu = (flags & 1) != 0;
#pragma unroll
    for (int m = 0; m < 4; ++m) {
        const int gr0 = tM + wr * 64 + m * 16 + (lane >> 4) * 4;
#pragma unroll
        for (int n = 0; n < 4; ++n) {
            const int gc = tN + wc * 64 + n * 16 + (lane & 15);
            const float bb = bias ? bias[gc] : 0.f;
#pragma unroll
            for (int j = 0; j < 4; ++j) {
                float v = acc[m][n][j] + bb;
                if (relu) v = fmaxf(v, 0.f);
                const long idx = cbase + (long)(gr0 + j) * ldc + gc;
                if (Cb) Cb[idx] = (__bf16)v;
                else Cf[idx] = v;
            }
        }
    }
}

// ---------------------------------------------------------------------------
// LayerNorm over D=1024, one block/row, bf16 out. (used for LN1)
// ---------------------------------------------------------------------------
__global__ __launch_bounds__(256) void ln_bf16(
    const float* __restrict__ x, const float* __restrict__ g,
    const float* __restrict__ bb, __bf16* __restrict__ out)
{
    const long row = blockIdx.x;
    const float* xr = x + row * ND;
    __bf16* orow = out + row * ND;
    const int t = threadIdx.x;
    float4 v = reinterpret_cast<const float4*>(xr)[t];
    float s = v.x + v.y + v.z + v.w;
    float s2 = v.x * v.x + v.y * v.y + v.z * v.z + v.w * v.w;
#pragma unroll
    for (int o = 32; o > 0; o >>= 1) {
        s += __shfl_xor(s, o, 64);
        s2 += __shfl_xor(s2, o, 64);
    }
    __shared__ float red[8];
    const int lane = t & 63, wv = t >> 6;
    if (lane == 0) { red[wv] = s; red[4 + wv] = s2; }
    __syncthreads();
    s = red[0] + red[1] + red[2] + red[3];
    s2 = red[4] + red[5] + red[6] + red[7];
    const float mean = s * (1.f / ND);
    const float var = s2 * (1.f / ND) - mean * mean;
    const float rs = rsqrtf(var + 1e-5f);
    const float xv[4] = {v.x, v.y, v.z, v.w};
    bf16x4 o;
#pragma unroll
    for (int j = 0; j < 4; ++j) {
        const int c = t * 4 + j;
        o[j] = (__bf16)((xv[j] - mean) * rs * g[c] + bb[c]);
    }
    *(bf16x4*)&orow[t * 4] = o;
}

// ---------------------------------------------------------------------------
// Fused weight prep: all fp32->bf16 transposes in one launch.
// ---------------------------------------------------------------------------
__global__ void prep_weights(
    const float* __restrict__ Wq, const float* __restrict__ Wk,
    const float* __restrict__ Wv, const float* __restrict__ Wo,
    const float* __restrict__ W1, const float* __restrict__ W2,
    const float* __restrict__ relv,
    __bf16* __restrict__ WqkvT, __bf16* __restrict__ WoT,
    __bf16* __restrict__ W1T, __bf16* __restrict__ W2T,
    __bf16* __restrict__ relvT, int R)
{
    const int tile = blockIdx.x;
    const float* src; __bf16* dst;
    int rows_in, cols_in, ldo, kx, ny;
    if (tile < 4096) {
        const int m = tile >> 10, r = tile & 1023;
        kx = r & 31; ny = r >> 5;
        rows_in = 1024; cols_in = 1024; ldo = 1024;
        src = m == 0 ? Wq : m == 1 ? Wk : m == 2 ? Wv : Wo;
        dst = m == 3 ? WoT : WqkvT + (size_t)m * 1024 * 1024;
    } else if (tile < 8192) {
        const int r = tile - 4096;
        kx = r & 31; ny = r >> 5;
        rows_in = 1024; cols_in = 4096; ldo = 1024; src = W1; dst = W1T;
    } else if (tile < 12288) {
        const int r = tile - 8192;
        kx = r & 127; ny = r >> 7;
        rows_in = 4096; cols_in = 1024; ldo = 4096; src = W2; dst = W2T;
    } else {
        const int r = tile - 12288;
        kx = r & 1; ny = r >> 1;
        rows_in = R; cols_in = 128; ldo = 64; src = relv; dst = relvT;
    }

    __shared__ float tl[32][33];
    const int k0 = kx * 32, n0 = ny * 32;
    const int tx = threadIdx.x, ty = threadIdx.y;
#pragma unroll
    for (int dy = 0; dy < 32; dy += 8) {
        const int k = k0 + ty + dy, n = n0 + tx;
        tl[ty + dy][tx] = (k < rows_in && n < cols_in) ? src[(long)k * cols_in + n] : 0.f;
    }
    __syncthreads();
#pragma unroll
    for (int dy = 0; dy < 32; dy += 8) {
        const int n = n0 + ty + dy, k = k0 + tx;
        if (n < cols_in && k < ldo) dst[(long)n * ldo + k] = (__bf16)tl[tx][ty + dy];
    }
}

// pack_bias + relk pad in one launch (grid 76 x 256)
__global__ void prep_small(const float* __restrict__ bq, const float* __restrict__ bk,
                           const float* __restrict__ bv, const float* __restrict__ relk,
                           float* __restrict__ biasqkv, __bf16* __restrict__ relkT, int R)
{
    const int t = blockIdx.x * 256 + threadIdx.x;
    if (t < ND) biasqkv[t] = bq[t];
    else if (t < 2 * ND) biasqkv[t] = bk[t - ND];
    else if (t < 3 * ND) biasqkv[t] = bv[t - 2 * ND];
    else {
        const int idx = t - 3 * ND;
        if (idx < 128 * NDK) {
            const int r = idx / NDK;
            relkT[idx] = (r < R) ? (__bf16)relk[idx] : (__bf16)0.f;
        }
    }
}

// QKV split-K reduce: qkvb = bf16(sum_4 partials + biasqkv)
__global__ __launch_bounds__(256) void qkv_reduce(
    const float* __restrict__ P, const float* __restrict__ bias,
    __bf16* __restrict__ qkvb)
{
    const long i4 = (long)blockIdx.x * 256 + threadIdx.x;  // float4 idx, 786432 total
    const long sP = (long)BSROWS * 3 * ND / 4;
    const float4* P4 = (const float4*)P;
    float4 s = P4[i4];
#pragma unroll
    for (int sp = 1; sp < 4; ++sp) {
        const float4 t = P4[i4 + sp * sP];
        s.x += t.x; s.y += t.y; s.z += t.z; s.w += t.w;
    }
    const int col4 = (int)(i4 % 768);
    const float4 bv = *(const float4*)&bias[col4 * 4];
    bf16x4 o;
    o[0] = (__bf16)(s.x + bv.x); o[1] = (__bf16)(s.y + bv.y);
    o[2] = (__bf16)(s.z + bv.z); o[3] = (__bf16)(s.w + bv.w);
    *(bf16x4*)&qkvb[i4 * 4] = o;
}

// FFN1 split-K reduce: F1 = bf16(relu(sum_2 partials + b1))
__global__ __launch_bounds__(256) void ffn1_reduce(
    const float* __restrict__ P, const float* __restrict__ b1,
    __bf16* __restrict__ F1)
{
    const long i4 = (long)blockIdx.x * 256 + threadIdx.x;  // 1048576 total
    const long sP = (long)BSROWS * NDFF / 4;
    const float4* P4 = (const float4*)P;
    float4 s = P4[i4];
    const float4 t1 = P4[i4 + sP];
    s.x += t1.x; s.y += t1.y; s.z += t1.z; s.w += t1.w;
    const int col4 = (int)(i4 & 1023);
    const float4 bv = *(const float4*)&b1[col4 * 4];
    bf16x4 o;
    o[0] = (__bf16)fmaxf(s.x + bv.x, 0.f); o[1] = (__bf16)fmaxf(s.y + bv.y, 0.f);
    o[2] = (__bf16)fmaxf(s.z + bv.z, 0.f); o[3] = (__bf16)fmaxf(s.w + bv.w, 0.f);
    *(bf16x4*)&F1[i4 * 4] = o;
}

// V slice of packed qkvb [1024,3072] -> vt [B,H,DK,S] bf16
__global__ void transpose_v(const __bf16* __restrict__ qkvb, __bf16* __restrict__ vt)
{
    __shared__ __bf16 tile[32][33];
    const int bh = blockIdx.z, b = bh >> 3, h = bh & 7;
    const int d0 = blockIdx.x * 32, i0 = blockIdx.y * 32;
    const int tx = threadIdx.x, ty = threadIdx.y;
    const __bf16* src = qkvb + 2 * ND + h * NDK;
#pragma unroll
    for (int dy = 0; dy < 32; dy += 8)
        tile[ty + dy][tx] = src[(long)(b * NS + i0 + ty + dy) * (3 * ND) + d0 + tx];
    __syncthreads();
#pragma unroll
    for (int dy = 0; dy < 32; dy += 8)
        vt[((long)bh * NDK + d0 + ty + dy) * NS + i0 + tx] = tile[tx][ty + dy];
}

// ---------------------------------------------------------------------------
// Fused softmax + relation gather + attnR binning + history-loss partial.
// ---------------------------------------------------------------------------
__global__ __launch_bounds__(256) void softmax_rel(
    const float* __restrict__ scores, const float* __restrict__ qr,
    const int* __restrict__ relation, const int* __restrict__ mask,
    __bf16* __restrict__ attn, __bf16* __restrict__ attnR,
    float* __restrict__ loss_part, const int* __restrict__ sep_p)
{
    const int i = blockIdx.x, h = blockIdx.y, b = blockIdx.z;
    const long bh = (long)(b * NH + h);
    const float* srow = scores + (bh * NS + i) * NS;
    const float* qrow = qr + (bh * NS + i) * QRLD;
    const int* rrow = relation + ((long)b * NS + i) * NS;
    const int* mrow = mask + ((long)b * NS + i) * NS;
    __bf16* arow = attn + (bh * NS + i) * NS;
    __bf16* aRrow = attnR + (bh * NS + i) * RPAD;

    __shared__ float qrl[RPAD];
    __shared__ float bins[RPAD];
    __shared__ float red[4];

    const int t = threadIdx.x;
    const float s0 = srow[t], s1 = srow[t + 256];
    const int r0 = rrow[t], r1 = rrow[t + 256];
    const int m0 = mrow[t], m1 = mrow[t + 256];
    if (t < RPAD) { qrl[t] = qrow[t]; bins[t] = 0.f; }
    __syncthreads();

    const float sc = 0.088388347648318447f;  // 1/sqrt(128)
    float v0 = (s0 + qrl[r0]) * sc;
    float v1 = (s1 + qrl[r1]) * sc;
    if (m0 == 0) v0 = -1e9f;
    if (m1 == 0) v1 = -1e9f;

    const int lane = t & 63, wv = t >> 6;

    float mx = fmaxf(v0, v1);
#pragma unroll
    for (int o = 32; o > 0; o >>= 1) mx = fmaxf(mx, __shfl_xor(mx, o, 64));
    if (lane == 0) red[wv] = mx;
    __syncthreads();
    mx = fmaxf(fmaxf(red[0], red[1]), fmaxf(red[2], red[3]));
    __syncthreads();

    const float e0 = __expf(v0 - mx), e1 = __expf(v1 - mx);
    float sm = e0 + e1;
#pragma unroll
    for (int o = 32; o > 0; o >>= 1) sm += __shfl_xor(sm, o, 64);
    if (lane == 0) red[wv] = sm;
    __syncthreads();
    sm = red[0] + red[1] + red[2] + red[3];
    __syncthreads();

    const float inv = 1.f / sm;
    const float a0 = e0 * inv, a1 = e1 * inv;
    arow[t] = (__bf16)a0;
    arow[t + 256] = (__bf16)a1;
    atomicAdd(&bins[r0], a0);
    atomicAdd(&bins[r1], a1);

    const int sep = *sep_p;
    float ls = 0.f;
    if (t < sep) ls += a0;
    if (t + 256 < sep) ls += a1;
#pragma unroll
    for (int o = 32; o > 0; o >>= 1) ls += __shfl_xor(ls, o, 64);
    if (lane == 0) red[wv] = ls;
    __syncthreads();  // also fences bins atomics
    if (t == 0) loss_part[bh * NS + i] = red[0] + red[1] + red[2] + red[3];
    if (t < RPAD) aRrow[t] = (__bf16)bins[t];
}

// ctx split-K reduce + fused attnR@rel_v + merge_heads -> ctxm bf16 [B*S, D]
__global__ __launch_bounds__(256) void ctx_reduce(
    const float* __restrict__ P, const __bf16* __restrict__ attnR,
    const __bf16* __restrict__ relvT, __bf16* __restrict__ ctxm)
{
    const int idx = blockIdx.x * 256 + threadIdx.x;  // bh*65536 + i*128 + d
    const int d = idx & 127;
    const int i = (idx >> 7) & 511;
    const int h = (idx >> 16) & 7;
    const int b = idx >> 19;
    const long sP = (long)NBH * NS * NDK;
    float s = P[idx] + P[idx + sP] + P[idx + 2 * sP] + P[idx + 3 * sP];

    const bf16x8* ar = (const bf16x8*)(attnR + ((long)(idx >> 16) * NS + i) * RPAD);
    const bf16x8* rv = (const bf16x8*)(relvT + (long)d * RPAD);
    float acc = 0.f;
#pragma unroll
    for (int q = 0; q < 8; ++q) {
        bf16x8 a = ar[q], vv = rv[q];
#pragma unroll
        for (int j = 0; j < 8; ++j) acc += (float)a[j] * (float)vv[j];
    }
    ctxm[((long)(b * NS + i)) * ND + h * NDK + d] = (__bf16)(s + acc);
}

// Wo split-K(8) reduce + residual + bias, fused LN2 -> out fp32 + h2 bf16.
// One block per row (256 thr x float4 = 1024 cols).
__global__ __launch_bounds__(256) void wo_reduce_ln(
    const float* __restrict__ P, const float* __restrict__ x,
    const float* __restrict__ bo, const float* __restrict__ g,
    const float* __restrict__ bb, float* __restrict__ out,
    __bf16* __restrict__ h2)
{
    const int row = blockIdx.x;
    const int t = threadIdx.x;
    const long i4 = (long)row * 256 + t;
    const long sP = (long)BSROWS * ND / 4;
    const float4* P4 = (const float4*)P;
    float4 s = P4[i4];
#pragma unroll
    for (int sp = 1; sp < 8; ++sp) {
        const float4 tt = P4[i4 + sp * sP];
        s.x += tt.x; s.y += tt.y; s.z += tt.z; s.w += tt.w;
    }
    const int col = t * 4;
    const float4 xv = ((const float4*)x)[i4];
    const float4 bv = *(const float4*)&bo[col];
    float4 o;
    o.x = s.x + xv.x + bv.x; o.y = s.y + xv.y + bv.y;
    o.z = s.z + xv.z + bv.z; o.w = s.w + xv.w + bv.w;
    ((float4*)out)[i4] = o;

    // fused LN2
    float sum = o.x + o.y + o.z + o.w;
    float sum2 = o.x * o.x + o.y * o.y + o.z * o.z + o.w * o.w;
#pragma unroll
    for (int of = 32; of > 0; of >>= 1) {
        sum += __shfl_xor(sum, of, 64);
        sum2 += __shfl_xor(sum2, of, 64);
    }
    __shared__ float red[8];
    const int lane = t & 63, wv = t >> 6;
    if (lane == 0) { red[wv] = sum; red[4 + wv] = sum2; }
    __syncthreads();
    sum = red[0] + red[1] + red[2] + red[3];
    sum2 = red[4] + red[5] + red[6] + red[7];
    const float mean = sum * (1.f / ND);
    const float var = sum2 * (1.f / ND) - mean * mean;
    const float rs = rsqrtf(var + 1e-5f);
    const float ov[4] = {o.x, o.y, o.z, o.w};
    bf16x4 hb;
#pragma unroll
    for (int j = 0; j < 4; ++j)
        hb[j] = (__bf16)((ov[j] - mean) * rs * g[col + j] + bb[col + j]);
    *(bf16x4*)&h2[(long)row * ND + col] = hb;
}

// FFN2 split-K reduce: out += b2 + sum_8 partials
__global__ __launch_bounds__(256) void ffn2_reduce(
    const float* __restrict__ P, const float* __restrict__ b2, float* __restrict__ out)
{
    const int i4 = blockIdx.x * 256 + threadIdx.x;
    const long sP = (long)BSROWS * ND / 4;
    const float4* P4 = (const float4*)P;
    float4 s = P4[i4];
#pragma unroll
    for (int sp = 1; sp < 8; ++sp) {
        const float4 t = P4[i4 + sp * sP];
        s.x += t.x; s.y += t.y; s.z += t.z; s.w += t.w;
    }
    const int col = (i4 * 4) & (ND - 1);
    const float4 bv = *(const float4*)&b2[col];
    float4 o = ((float4*)out)[i4];
    o.x += s.x + bv.x; o.y += s.y + bv.y;
    o.z += s.z + bv.z; o.w += s.w + bv.w;
    ((float4*)out)[i4] = o;
}

// Reduce 8192 per-row loss partials in one block.
__global__ __launch_bounds__(256) void finalize_loss(
    const float* __restrict__ loss_part, const float* __restrict__ hist,
    const int* __restrict__ sep_p, float* __restrict__ out_loss)
{
    const int t = threadIdx.x;
    float s = 0.f;
#pragma unroll
    for (int k = 0; k < NBH * NS / 1024; ++k) {
        const float4 v = ((const float4*)loss_part)[t + k * 256];
        s += v.x + v.y + v.z + v.w;
    }
#pragma unroll
    for (int o = 32; o > 0; o >>= 1) s += __shfl_xor(s, o, 64);
    __shared__ float red[4];
    if ((t & 63) == 0) red[t >> 6] = s;
    __syncthreads();
    if (t == 0) {
        const int sep = *sep_p;
        const float total = red[0] + red[1] + red[2] + red[3];
        const float denom = (float)NB * NH * NS * (float)(sep > 0 ? sep : 1);
        out_loss[0] = (sep > 0) ? hist[0] * total / denom : 0.f;
    }
}

// ---------------------------------------------------------------------------
static inline int cdiv(int a, int b) { return (a + b - 1) / b; }

extern "C" void kernel_launch(void* const* d_in, const int* in_sizes, int n_in,
                              void* d_out, int out_size, void* d_ws, size_t ws_size,
                              hipStream_t stream)
{
    const float* x      = (const float*)d_in[0];
    const int* relation = (const int*)d_in[1];
    const int* mask     = (const int*)d_in[2];
    const int* sep_p    = (const int*)d_in[3];
    const float* hist   = (const float*)d_in[4];
    const float* Wq = (const float*)d_in[5],  *bq = (const float*)d_in[6];
    const float* Wk = (const float*)d_in[7],  *bk = (const float*)d_in[8];
    const float* Wv = (const float*)d_in[9],  *bv = (const float*)d_in[10];
    const float* Wo = (const float*)d_in[11], *bo = (const float*)d_in[12];
    const float* relk = (const float*)d_in[13];
    const float* relv = (const float*)d_in[14];
    const float* ln1g = (const float*)d_in[15], *ln1b = (const float*)d_in[16];
    const float* ln2g = (const float*)d_in[17], *ln2b = (const float*)d_in[18];
    const float* W1 = (const float*)d_in[19], *b1 = (const float*)d_in[20];
    const float* W2 = (const float*)d_in[21], *b2 = (const float*)d_in[22];
    const int R = in_sizes[13] / NDK;  // 51

    float* out = (float*)d_out;
    float* out_loss = out + (long)BSROWS * ND;

    char* p = (char*)d_ws;
    auto alloc = [&](size_t bytes) -> void* {
        void* r = (void*)p;
        p += (bytes + 255) & ~(size_t)255;
        return r;
    };
    __bf16* WqkvT   = (__bf16*)alloc((size_t)3 * ND * ND * 2);
    __bf16* WoT     = (__bf16*)alloc((size_t)ND * ND * 2);
    __bf16* W1T     = (__bf16*)alloc((size_t)NDFF * ND * 2);
    __bf16* W2T     = (__bf16*)alloc((size_t)ND * NDFF * 2);
    __bf16* relkT   = (__bf16*)alloc((size_t)128 * NDK * 2);
    __bf16* relvT   = (__bf16*)alloc((size_t)NDK * RPAD * 2);
    float*  biasqkv = (float*)alloc((size_t)3 * ND * 4);
    __bf16* h1      = (__bf16*)alloc((size_t)BSROWS * ND * 2);
    __bf16* qkvb    = (__bf16*)alloc((size_t)BSROWS * 3 * ND * 2);
    __bf16* vt      = (__bf16*)alloc((size_t)NBH * NDK * NS * 2);
    float*  qr      = (float*)alloc((size_t)NBH * NS * QRLD * 4);
    __bf16* attnb   = (__bf16*)alloc((size_t)NBH * NS * NS * 2);
    __bf16* attnR   = (__bf16*)alloc((size_t)NBH * NS * RPAD * 2);
    __bf16* ctxm    = (__bf16*)alloc((size_t)BSROWS * ND * 2);
    __bf16* h2      = (__bf16*)alloc((size_t)BSROWS * ND * 2);
    __bf16* F1      = (__bf16*)alloc((size_t)BSROWS * NDFF * 2);
    float*  loss_part = (float*)alloc((size_t)NBH * NS * 4);
    float*  arena   = (float*)alloc((size_t)64 * 1024 * 1024);
    // arena aliasing (lifetimes disjoint), offsets in floats:
    float* qkvPart = arena;                            // 48MB [0,48)
    float* scoresb = arena;                            // 16MB [0,16)
    float* ctxPart = arena + (size_t)4 * 1024 * 1024;  // 16MB [16,32)
    float* woPart  = arena;                            // 32MB [0,32)
    float* ffn1Part= arena;                            // 32MB [0,32)
    float* f2Part  = arena + (size_t)8 * 1024 * 1024;  // 32MB [32,64)

    const dim3 tb(32, 8);
    prep_weights<<<12296, tb, 0, stream>>>(Wq, Wk, Wv, Wo, W1, W2, relv,
                                           WqkvT, WoT, W1T, W2T, relvT, R);
    prep_small<<<76, 256, 0, stream>>>(bq, bk, bv, relk, biasqkv, relkT, R);

    ln_bf16<<<BSROWS, 256, 0, stream>>>(x, ln1g, ln1b, h1);

    // QKV: [1024,1024] @ [3072,1024]^T, split-K x4 (Ksp=256, nt=4) -> 768 blocks
    gemm128<<<dim3(24, 8, 4), 256, 0, stream>>>(
        h1, WqkvT, qkvPart, nullptr, nullptr,
        256, ND, ND, 3 * ND,
        0, 0, 1, 0, 0, 1,
        0, 4, (long)BSROWS * 3 * ND, 0);

    qkv_reduce<<<3072, 256, 0, stream>>>(qkvPart, biasqkv, qkvb);

    transpose_v<<<dim3(4, 16, NBH), tb, 0, stream>>>(qkvb, vt);

    // qr[bh,i,r] = q . rel_k : per-head A = qkvb col-slice, K=128 (nt=2)
    gemm128<<<dim3(1, 4, NBH), 256, 0, stream>>>(
        qkvb, relkT, qr, nullptr, nullptr,
        NDK, 3 * ND, NDK, QRLD,
        (long)NS * 3 * ND, NDK, NH,
        0, 0, 1,
        (long)NS * QRLD, 1, 0, 0);

    // scores = q @ k^T (per-head col-slices of qkvb, nt=2)
    gemm128<<<dim3(4, 4, NBH), 256, 0, stream>>>(
        qkvb, qkvb + ND, scoresb, nullptr, nullptr,
        NDK, 3 * ND, 3 * ND, NS,
        (long)NS * 3 * ND, NDK, NH,
        (long)NS * 3 * ND, NDK, NH,
        (long)NS * NS, 1, 0, 0);

    softmax_rel<<<dim3(NS, NH, NB), 256, 0, stream>>>(
        scoresb, qr, relation, mask, attnb, attnR, loss_part, sep_p);

    // ctx = attn @ v : split-K x4 (Ksp=128, nt=2), batch 16 -> 256 blocks
    gemm128<<<dim3(1, 4, NBH * 4), 256, 0, stream>>>(
        attnb, vt, ctxPart, nullptr, nullptr,
        128, NS, NS, NDK,
        (long)NS * NS, 0, 1,
        (long)NDK * NS, 0, 1,
        (long)NS * NDK, 4, (long)NBH * NS * NDK, 0);

    ctx_reduce<<<4096, 256, 0, stream>>>(ctxPart, attnR, relvT, ctxm);

    // attn_out partials: ctxm @ Wo, split-K x8 (Ksp=128, nt=2) -> 512 blocks
    gemm128<<<dim3(8, 8, 8), 256, 0, stream>>>(
        ctxm, WoT, woPart, nullptr, nullptr,
        128, ND, ND, ND,
        0, 0, 1, 0, 0, 1,
        0, 8, (long)BSROWS * ND, 0);

    // fused: out = x + bo + sum partials; h2 = LN2(out)
    wo_reduce_ln<<<BSROWS, 256, 0, stream>>>(woPart, x, bo, ln2g, ln2b, out, h2);

    // FFN1 partials: h2 @ W1, split-K x2 (Ksp=512, nt=8) -> 512 blocks
    gemm128<<<dim3(32, 8, 2), 256, 0, stream>>>(
        h2, W1T, ffn1Part, nullptr, nullptr,
        512, ND, ND, NDFF,
        0, 0, 1, 0, 0, 1,
        0, 2, (long)BSROWS * NDFF, 0);

    ffn1_reduce<<<4096, 256, 0, stream>>>(ffn1Part, b1, F1);

    // FFN2 partials: F1 @ W2, split-K x8 (Ksp=512, nt=8) -> 512 blocks
    gemm128<<<dim3(8, 8, 8), 256, 0, stream>>>(
        F1, W2T, f2Part, nullptr, nullptr,
        512, NDFF, NDFF, ND,
        0, 0, 1, 0, 0, 1,
        0, 8, (long)BSROWS * ND, 0);

    ffn2_reduce<<<1024, 256, 0, stream>>>(f2Part, b2, out);

    finalize_loss<<<1, 256, 0, stream>>>(loss_part, hist, sep_p, out_loss);
}

// Round 6
// 199.605 us; speedup vs baseline: 1.1234x; 1.1234x over previous
//
#include <hip/hip_runtime.h>
#include <hip/hip_bf16.h>

#define NB 2
#define NS 512
#define ND 1024
#define NH 8
#define NDK 128
#define NDFF 4096
#define QRLD 128
#define RPAD 64
#define BSROWS 1024           /* B*S */
#define NBH 16                /* B*H */

typedef __bf16 bf16x8 __attribute__((ext_vector_type(8)));
typedef __bf16 bf16x4 __attribute__((ext_vector_type(4)));
typedef float f32x4 __attribute__((ext_vector_type(4)));

#define BM 128
#define BN 128
#define BK 64

__device__ __forceinline__ void gload16(const void* g, void* l) {
    __builtin_amdgcn_global_load_lds(
        (const __attribute__((address_space(1))) void*)g,
        (__attribute__((address_space(3))) void*)l, 16, 0, 0);
}

// ---------------------------------------------------------------------------
// Counted-vmcnt pipelined MFMA GEMM: C[M,N] = A[M,K] @ Bt[N,K]^T.
// 128x128 tile, BK=64, 4 waves. 2 LDS buffers, loads stay in flight across
// barriers (T4): prologue stages t0,t1; iter t waits vmcnt(8) (t's 8 loads
// done, t+1's still flying), computes, re-stages buf for t+2 after a raw
// barrier. LDS XOR-swizzle (T2) applied on the GLOBAL source address
// (global_load_lds dest must stay linear) and inverted on the ds_read.
// Requires nt = Ksp/BK even and >= 2.
// ---------------------------------------------------------------------------
__global__ __launch_bounds__(256) void gemm128(
    const __bf16* __restrict__ A, const __bf16* __restrict__ Bt,
    float* __restrict__ Cf, __bf16* __restrict__ Cb,
    const float* __restrict__ bias,
    int Ksp, int lda, int ldb, int ldc,
    long sA, long sA2, int zdivA,
    long sB, long sB2, int zdivB,
    long sC, int nsplit, long sPart, int flags)
{
    __shared__ __bf16 As0[BM * BK];
    __shared__ __bf16 As1[BM * BK];
    __shared__ __bf16 Bs0[BN * BK];
    __shared__ __bf16 Bs1[BN * BK];

    const int z = blockIdx.z;
    const int bh = z / nsplit, sp = z - bh * nsplit;
    const long kbase = (long)sp * Ksp;
    A  += (long)(bh / zdivA) * sA + (long)(bh % zdivA) * sA2 + kbase;
    Bt += (long)(bh / zdivB) * sB + (long)(bh % zdivB) * sB2 + kbase;
    const long cbase = (long)bh * sC + (long)sp * sPart;

    const int tM = blockIdx.y * BM, tN = blockIdx.x * BN;
    const int t = threadIdx.x, lane = t & 63, w = t >> 6;
    const int wr = w >> 1, wc = w & 1;

    // staging source address: row = lane>>3 within 8-row chunk; byte col
    // pre-swizzled so linear LDS ends up XOR-swizzled: c_src = c_lds ^ (row&7)<<4
    const int srow = lane >> 3;
    const int scolE = ((((lane & 7) << 4) ^ (srow << 4)) >> 1);  // element col

    const __bf16* gA = A + (long)(tM + srow) * lda + scolE;
    const __bf16* gB = Bt + (long)(tN + srow) * ldb + scolE;

    f32x4 acc[4][4];
#pragma unroll
    for (int m = 0; m < 4; ++m)
#pragma unroll
        for (int n = 0; n < 4; ++n)
#pragma unroll
            for (int j = 0; j < 4; ++j) acc[m][n][j] = 0.f;

    const int r16 = lane & 15;
    const int kq = (lane >> 4) * 8;
    const int xorE = (r16 & 7) * 8;     // read-side element XOR (== (row&7)<<4 bytes)
    const int nt = Ksp / BK;

    auto STAGE = [&](__bf16* as, __bf16* bs, int k0) {
#pragma unroll
        for (int i = 0; i < 4; ++i) {
            const int rr = (w * 4 + i) * 8;   // wave-uniform 8-row chunk base
            gload16(gA + (long)rr * lda + k0, (void*)&as[rr * BK]);
            gload16(gB + (long)rr * ldb + k0, (void*)&bs[rr * BK]);
        }
    };
    auto COMPUTE = [&](const __bf16* as, const __bf16* bs) {
#pragma unroll
        for (int ks = 0; ks < 2; ++ks) {
            bf16x8 af[4], bv[4];
#pragma unroll
            for (int m = 0; m < 4; ++m)
                af[m] = *(const bf16x8*)&as[(wr * 64 + m * 16 + r16) * BK + ((ks * 32 + kq) ^ xorE)];
#pragma unroll
            for (int n = 0; n < 4; ++n)
                bv[n] = *(const bf16x8*)&bs[(wc * 64 + n * 16 + r16) * BK + ((ks * 32 + kq) ^ xorE)];
#pragma unroll
            for (int m = 0; m < 4; ++m)
#pragma unroll
                for (int n = 0; n < 4; ++n)
                    acc[m][n] = __builtin_amdgcn_mfma_f32_16x16x32_bf16(af[m], bv[n], acc[m][n], 0, 0, 0);
        }
    };

    STAGE(As0, Bs0, 0);        // 8 loads
    STAGE(As1, Bs1, BK);       // 16 in flight
    for (int tt = 0; tt < nt; tt += 2) {
        // buf0 (tile tt) ready when own outstanding <= 8 (tile tt+1's loads)
        asm volatile("s_waitcnt vmcnt(8)\n\ts_barrier" ::: "memory");
        COMPUTE(As0, Bs0);
        asm volatile("s_waitcnt lgkmcnt(0)\n\ts_barrier" ::: "memory");
        const bool more = (tt + 2 < nt);   // nt even => tt+3 < nt too
        if (more) {
            STAGE(As0, Bs0, (tt + 2) * BK);                    // 16 in flight
            asm volatile("s_waitcnt vmcnt(8)\n\ts_barrier" ::: "memory");
        } else {
            asm volatile("s_waitcnt vmcnt(0)\n\ts_barrier" ::: "memory");
        }
        COMPUTE(As1, Bs1);
        asm volatile("s_waitcnt lgkmcnt(0)\n\ts_barrier" ::: "memory");
        if (more) STAGE(As1, Bs1, (tt + 3) * BK);
    }

    const bool relu = (flags & 1) != 0;
#pragma unroll
    for (int m = 0; m < 4; ++m) {
        const int gr0 = tM + wr * 64 + m * 16 + (lane >> 4) * 4;
#pragma unroll
        for (int n = 0; n < 4; ++n) {
            const int gc = tN + wc * 64 + n * 16 + (lane & 15);
            const float bb = bias ? bias[gc] : 0.f;
#pragma unroll
            for (int j = 0; j < 4; ++j) {
                float v = acc[m][n][j] + bb;
                if (relu) v = fmaxf(v, 0.f);
                const long idx = cbase + (long)(gr0 + j) * ldc + gc;
                if (Cb) Cb[idx] = (__bf16)v;
                else Cf[idx] = v;
            }
        }
    }
}

// ---------------------------------------------------------------------------
// LayerNorm over D=1024, one block/row, bf16 out. (LN1)
// ---------------------------------------------------------------------------
__global__ __launch_bounds__(256) void ln_bf16(
    const float* __restrict__ x, const float* __restrict__ g,
    const float* __restrict__ bb, __bf16* __restrict__ out)
{
    const long row = blockIdx.x;
    const float* xr = x + row * ND;
    __bf16* orow = out + row * ND;
    const int t = threadIdx.x;
    float4 v = reinterpret_cast<const float4*>(xr)[t];
    float s = v.x + v.y + v.z + v.w;
    float s2 = v.x * v.x + v.y * v.y + v.z * v.z + v.w * v.w;
#pragma unroll
    for (int o = 32; o > 0; o >>= 1) {
        s += __shfl_xor(s, o, 64);
        s2 += __shfl_xor(s2, o, 64);
    }
    __shared__ float red[8];
    const int lane = t & 63, wv = t >> 6;
    if (lane == 0) { red[wv] = s; red[4 + wv] = s2; }
    __syncthreads();
    s = red[0] + red[1] + red[2] + red[3];
    s2 = red[4] + red[5] + red[6] + red[7];
    const float mean = s * (1.f / ND);
    const float var = s2 * (1.f / ND) - mean * mean;
    const float rs = rsqrtf(var + 1e-5f);
    const float xv[4] = {v.x, v.y, v.z, v.w};
    bf16x4 o;
#pragma unroll
    for (int j = 0; j < 4; ++j) {
        const int c = t * 4 + j;
        o[j] = (__bf16)((xv[j] - mean) * rs * g[c] + bb[c]);
    }
    *(bf16x4*)&orow[t * 4] = o;
}

// ---------------------------------------------------------------------------
// Fused weight prep: all fp32->bf16 transposes in one launch.
// ---------------------------------------------------------------------------
__global__ void prep_weights(
    const float* __restrict__ Wq, const float* __restrict__ Wk,
    const float* __restrict__ Wv, const float* __restrict__ Wo,
    const float* __restrict__ W1, const float* __restrict__ W2,
    const float* __restrict__ relv,
    __bf16* __restrict__ WqkvT, __bf16* __restrict__ WoT,
    __bf16* __restrict__ W1T, __bf16* __restrict__ W2T,
    __bf16* __restrict__ relvT, int R)
{
    const int tile = blockIdx.x;
    const float* src; __bf16* dst;
    int rows_in, cols_in, ldo, kx, ny;
    if (tile < 4096) {
        const int m = tile >> 10, r = tile & 1023;
        kx = r & 31; ny = r >> 5;
        rows_in = 1024; cols_in = 1024; ldo = 1024;
        src = m == 0 ? Wq : m == 1 ? Wk : m == 2 ? Wv : Wo;
        dst = m == 3 ? WoT : WqkvT + (size_t)m * 1024 * 1024;
    } else if (tile < 8192) {
        const int r = tile - 4096;
        kx = r & 31; ny = r >> 5;
        rows_in = 1024; cols_in = 4096; ldo = 1024; src = W1; dst = W1T;
    } else if (tile < 12288) {
        const int r = tile - 8192;
        kx = r & 127; ny = r >> 7;
        rows_in = 4096; cols_in = 1024; ldo = 4096; src = W2; dst = W2T;
    } else {
        const int r = tile - 12288;
        kx = r & 1; ny = r >> 1;
        rows_in = R; cols_in = 128; ldo = 64; src = relv; dst = relvT;
    }

    __shared__ float tl[32][33];
    const int k0 = kx * 32, n0 = ny * 32;
    const int tx = threadIdx.x, ty = threadIdx.y;
#pragma unroll
    for (int dy = 0; dy < 32; dy += 8) {
        const int k = k0 + ty + dy, n = n0 + tx;
        tl[ty + dy][tx] = (k < rows_in && n < cols_in) ? src[(long)k * cols_in + n] : 0.f;
    }
    __syncthreads();
#pragma unroll
    for (int dy = 0; dy < 32; dy += 8) {
        const int n = n0 + ty + dy, k = k0 + tx;
        if (n < cols_in && k < ldo) dst[(long)n * ldo + k] = (__bf16)tl[tx][ty + dy];
    }
}

// pack_bias + relk pad in one launch (grid 76 x 256)
__global__ void prep_small(const float* __restrict__ bq, const float* __restrict__ bk,
                           const float* __restrict__ bv, const float* __restrict__ relk,
                           float* __restrict__ biasqkv, __bf16* __restrict__ relkT, int R)
{
    const int t = blockIdx.x * 256 + threadIdx.x;
    if (t < ND) biasqkv[t] = bq[t];
    else if (t < 2 * ND) biasqkv[t] = bk[t - ND];
    else if (t < 3 * ND) biasqkv[t] = bv[t - 2 * ND];
    else {
        const int idx = t - 3 * ND;
        if (idx < 128 * NDK) {
            const int r = idx / NDK;
            relkT[idx] = (r < R) ? (__bf16)relk[idx] : (__bf16)0.f;
        }
    }
}

// V slice of packed qkvb [1024,3072] -> vt [B,H,DK,S] bf16
__global__ void transpose_v(const __bf16* __restrict__ qkvb, __bf16* __restrict__ vt)
{
    __shared__ __bf16 tile[32][33];
    const int bh = blockIdx.z, b = bh >> 3, h = bh & 7;
    const int d0 = blockIdx.x * 32, i0 = blockIdx.y * 32;
    const int tx = threadIdx.x, ty = threadIdx.y;
    const __bf16* src = qkvb + 2 * ND + h * NDK;
#pragma unroll
    for (int dy = 0; dy < 32; dy += 8)
        tile[ty + dy][tx] = src[(long)(b * NS + i0 + ty + dy) * (3 * ND) + d0 + tx];
    __syncthreads();
#pragma unroll
    for (int dy = 0; dy < 32; dy += 8)
        vt[((long)bh * NDK + d0 + ty + dy) * NS + i0 + tx] = tile[tx][ty + dy];
}

// ---------------------------------------------------------------------------
// Fused softmax + relation gather + attnR binning + history-loss partial.
// ---------------------------------------------------------------------------
__global__ __launch_bounds__(256) void softmax_rel(
    const float* __restrict__ scores, const float* __restrict__ qr,
    const int* __restrict__ relation, const int* __restrict__ mask,
    __bf16* __restrict__ attn, __bf16* __restrict__ attnR,
    float* __restrict__ loss_part, const int* __restrict__ sep_p)
{
    const int i = blockIdx.x, h = blockIdx.y, b = blockIdx.z;
    const long bh = (long)(b * NH + h);
    const float* srow = scores + (bh * NS + i) * NS;
    const float* qrow = qr + (bh * NS + i) * QRLD;
    const int* rrow = relation + ((long)b * NS + i) * NS;
    const int* mrow = mask + ((long)b * NS + i) * NS;
    __bf16* arow = attn + (bh * NS + i) * NS;
    __bf16* aRrow = attnR + (bh * NS + i) * RPAD;

    __shared__ float qrl[RPAD];
    __shared__ float bins[RPAD];
    __shared__ float red[4];

    const int t = threadIdx.x;
    const float s0 = srow[t], s1 = srow[t + 256];
    const int r0 = rrow[t], r1 = rrow[t + 256];
    const int m0 = mrow[t], m1 = mrow[t + 256];
    if (t < RPAD) { qrl[t] = qrow[t]; bins[t] = 0.f; }
    __syncthreads();

    const float sc = 0.088388347648318447f;  // 1/sqrt(128)
    float v0 = (s0 + qrl[r0]) * sc;
    float v1 = (s1 + qrl[r1]) * sc;
    if (m0 == 0) v0 = -1e9f;
    if (m1 == 0) v1 = -1e9f;

    const int lane = t & 63, wv = t >> 6;

    float mx = fmaxf(v0, v1);
#pragma unroll
    for (int o = 32; o > 0; o >>= 1) mx = fmaxf(mx, __shfl_xor(mx, o, 64));
    if (lane == 0) red[wv] = mx;
    __syncthreads();
    mx = fmaxf(fmaxf(red[0], red[1]), fmaxf(red[2], red[3]));
    __syncthreads();

    const float e0 = __expf(v0 - mx), e1 = __expf(v1 - mx);
    float sm = e0 + e1;
#pragma unroll
    for (int o = 32; o > 0; o >>= 1) sm += __shfl_xor(sm, o, 64);
    if (lane == 0) red[wv] = sm;
    __syncthreads();
    sm = red[0] + red[1] + red[2] + red[3];
    __syncthreads();

    const float inv = 1.f / sm;
    const float a0 = e0 * inv, a1 = e1 * inv;
    arow[t] = (__bf16)a0;
    arow[t + 256] = (__bf16)a1;
    atomicAdd(&bins[r0], a0);
    atomicAdd(&bins[r1], a1);

    const int sep = *sep_p;
    float ls = 0.f;
    if (t < sep) ls += a0;
    if (t + 256 < sep) ls += a1;
#pragma unroll
    for (int o = 32; o > 0; o >>= 1) ls += __shfl_xor(ls, o, 64);
    if (lane == 0) red[wv] = ls;
    __syncthreads();  // also fences bins atomics
    if (t == 0) loss_part[bh * NS + i] = red[0] + red[1] + red[2] + red[3];
    if (t < RPAD) aRrow[t] = (__bf16)bins[t];
}

// ctx split-K reduce + fused attnR@rel_v + merge_heads -> ctxm bf16 [B*S, D]
__global__ __launch_bounds__(256) void ctx_reduce(
    const float* __restrict__ P, const __bf16* __restrict__ attnR,
    const __bf16* __restrict__ relvT, __bf16* __restrict__ ctxm)
{
    const int idx = blockIdx.x * 256 + threadIdx.x;  // bh*65536 + i*128 + d
    const int d = idx & 127;
    const int i = (idx >> 7) & 511;
    const int h = (idx >> 16) & 7;
    const int b = idx >> 19;
    const long sP = (long)NBH * NS * NDK;
    float s = P[idx] + P[idx + sP] + P[idx + 2 * sP] + P[idx + 3 * sP];

    const bf16x8* ar = (const bf16x8*)(attnR + ((long)(idx >> 16) * NS + i) * RPAD);
    const bf16x8* rv = (const bf16x8*)(relvT + (long)d * RPAD);
    float acc = 0.f;
#pragma unroll
    for (int q = 0; q < 8; ++q) {
        bf16x8 a = ar[q], vv = rv[q];
#pragma unroll
        for (int j = 0; j < 8; ++j) acc += (float)a[j] * (float)vv[j];
    }
    ctxm[((long)(b * NS + i)) * ND + h * NDK + d] = (__bf16)(s + acc);
}

// Wo split-K(4) reduce + residual + bias, fused LN2 -> out fp32 + h2 bf16.
__global__ __launch_bounds__(256) void wo_reduce_ln(
    const float* __restrict__ P, const float* __restrict__ x,
    const float* __restrict__ bo, const float* __restrict__ g,
    const float* __restrict__ bb, float* __restrict__ out,
    __bf16* __restrict__ h2)
{
    const int row = blockIdx.x;
    const int t = threadIdx.x;
    const long i4 = (long)row * 256 + t;
    const long sP = (long)BSROWS * ND / 4;
    const float4* P4 = (const float4*)P;
    float4 s = P4[i4];
#pragma unroll
    for (int sp = 1; sp < 4; ++sp) {
        const float4 tt = P4[i4 + sp * sP];
        s.x += tt.x; s.y += tt.y; s.z += tt.z; s.w += tt.w;
    }
    const int col = t * 4;
    const float4 xv = ((const float4*)x)[i4];
    const float4 bv = *(const float4*)&bo[col];
    float4 o;
    o.x = s.x + xv.x + bv.x; o.y = s.y + xv.y + bv.y;
    o.z = s.z + xv.z + bv.z; o.w = s.w + xv.w + bv.w;
    ((float4*)out)[i4] = o;

    float sum = o.x + o.y + o.z + o.w;
    float sum2 = o.x * o.x + o.y * o.y + o.z * o.z + o.w * o.w;
#pragma unroll
    for (int of = 32; of > 0; of >>= 1) {
        sum += __shfl_xor(sum, of, 64);
        sum2 += __shfl_xor(sum2, of, 64);
    }
    __shared__ float red[8];
    const int lane = t & 63, wv = t >> 6;
    if (lane == 0) { red[wv] = sum; red[4 + wv] = sum2; }
    __syncthreads();
    sum = red[0] + red[1] + red[2] + red[3];
    sum2 = red[4] + red[5] + red[6] + red[7];
    const float mean = sum * (1.f / ND);
    const float var = sum2 * (1.f / ND) - mean * mean;
    const float rs = rsqrtf(var + 1e-5f);
    const float ov[4] = {o.x, o.y, o.z, o.w};
    bf16x4 hb;
#pragma unroll
    for (int j = 0; j < 4; ++j)
        hb[j] = (__bf16)((ov[j] - mean) * rs * g[col + j] + bb[col + j]);
    *(bf16x4*)&h2[(long)row * ND + col] = hb;
}

// FFN2 split-K reduce: out += b2 + sum_8 partials
__global__ __launch_bounds__(256) void ffn2_reduce(
    const float* __restrict__ P, const float* __restrict__ b2, float* __restrict__ out)
{
    const int i4 = blockIdx.x * 256 + threadIdx.x;
    const long sP = (long)BSROWS * ND / 4;
    const float4* P4 = (const float4*)P;
    float4 s = P4[i4];
#pragma unroll
    for (int sp = 1; sp < 8; ++sp) {
        const float4 t = P4[i4 + sp * sP];
        s.x += t.x; s.y += t.y; s.z += t.z; s.w += t.w;
    }
    const int col = (i4 * 4) & (ND - 1);
    const float4 bv = *(const float4*)&b2[col];
    float4 o = ((float4*)out)[i4];
    o.x += s.x + bv.x; o.y += s.y + bv.y;
    o.z += s.z + bv.z; o.w += s.w + bv.w;
    ((float4*)out)[i4] = o;
}

// Reduce 8192 per-row loss partials in one block.
__global__ __launch_bounds__(256) void finalize_loss(
    const float* __restrict__ loss_part, const float* __restrict__ hist,
    const int* __restrict__ sep_p, float* __restrict__ out_loss)
{
    const int t = threadIdx.x;
    float s = 0.f;
#pragma unroll
    for (int k = 0; k < NBH * NS / 1024; ++k) {
        const float4 v = ((const float4*)loss_part)[t + k * 256];
        s += v.x + v.y + v.z + v.w;
    }
#pragma unroll
    for (int o = 32; o > 0; o >>= 1) s += __shfl_xor(s, o, 64);
    __shared__ float red[4];
    if ((t & 63) == 0) red[t >> 6] = s;
    __syncthreads();
    if (t == 0) {
        const int sep = *sep_p;
        const float total = red[0] + red[1] + red[2] + red[3];
        const float denom = (float)NB * NH * NS * (float)(sep > 0 ? sep : 1);
        out_loss[0] = (sep > 0) ? hist[0] * total / denom : 0.f;
    }
}

// ---------------------------------------------------------------------------
static inline int cdiv(int a, int b) { return (a + b - 1) / b; }

extern "C" void kernel_launch(void* const* d_in, const int* in_sizes, int n_in,
                              void* d_out, int out_size, void* d_ws, size_t ws_size,
                              hipStream_t stream)
{
    const float* x      = (const float*)d_in[0];
    const int* relation = (const int*)d_in[1];
    const int* mask     = (const int*)d_in[2];
    const int* sep_p    = (const int*)d_in[3];
    const float* hist   = (const float*)d_in[4];
    const float* Wq = (const float*)d_in[5],  *bq = (const float*)d_in[6];
    const float* Wk = (const float*)d_in[7],  *bk = (const float*)d_in[8];
    const float* Wv = (const float*)d_in[9],  *bv = (const float*)d_in[10];
    const float* Wo = (const float*)d_in[11], *bo = (const float*)d_in[12];
    const float* relk = (const float*)d_in[13];
    const float* relv = (const float*)d_in[14];
    const float* ln1g = (const float*)d_in[15], *ln1b = (const float*)d_in[16];
    const float* ln2g = (const float*)d_in[17], *ln2b = (const float*)d_in[18];
    const float* W1 = (const float*)d_in[19], *b1 = (const float*)d_in[20];
    const float* W2 = (const float*)d_in[21], *b2 = (const float*)d_in[22];
    const int R = in_sizes[13] / NDK;  // 51

    float* out = (float*)d_out;
    float* out_loss = out + (long)BSROWS * ND;

    char* p = (char*)d_ws;
    auto alloc = [&](size_t bytes) -> void* {
        void* r = (void*)p;
        p += (bytes + 255) & ~(size_t)255;
        return r;
    };
    __bf16* WqkvT   = (__bf16*)alloc((size_t)3 * ND * ND * 2);
    __bf16* WoT     = (__bf16*)alloc((size_t)ND * ND * 2);
    __bf16* W1T     = (__bf16*)alloc((size_t)NDFF * ND * 2);
    __bf16* W2T     = (__bf16*)alloc((size_t)ND * NDFF * 2);
    __bf16* relkT   = (__bf16*)alloc((size_t)128 * NDK * 2);
    __bf16* relvT   = (__bf16*)alloc((size_t)NDK * RPAD * 2);
    float*  biasqkv = (float*)alloc((size_t)3 * ND * 4);
    __bf16* h1      = (__bf16*)alloc((size_t)BSROWS * ND * 2);
    __bf16* qkvb    = (__bf16*)alloc((size_t)BSROWS * 3 * ND * 2);
    __bf16* vt      = (__bf16*)alloc((size_t)NBH * NDK * NS * 2);
    float*  qr      = (float*)alloc((size_t)NBH * NS * QRLD * 4);
    __bf16* attnb   = (__bf16*)alloc((size_t)NBH * NS * NS * 2);
    __bf16* attnR   = (__bf16*)alloc((size_t)NBH * NS * RPAD * 2);
    __bf16* ctxm    = (__bf16*)alloc((size_t)BSROWS * ND * 2);
    __bf16* h2      = (__bf16*)alloc((size_t)BSROWS * ND * 2);
    __bf16* F1      = (__bf16*)alloc((size_t)BSROWS * NDFF * 2);
    float*  loss_part = (float*)alloc((size_t)NBH * NS * 4);
    float*  arena   = (float*)alloc((size_t)64 * 1024 * 1024);
    // arena aliasing (lifetimes disjoint), offsets in floats:
    float* scoresb = arena;                            // 16MB [0,16)
    float* ctxPart = arena + (size_t)4 * 1024 * 1024;  // 16MB [16,32)
    float* woPart  = arena;                            // 16MB [0,16)
    float* f2Part  = arena + (size_t)4 * 1024 * 1024;  // 32MB [16,48)

    const dim3 tb(32, 8);
    prep_weights<<<12296, tb, 0, stream>>>(Wq, Wk, Wv, Wo, W1, W2, relv,
                                           WqkvT, WoT, W1T, W2T, relvT, R);
    prep_small<<<76, 256, 0, stream>>>(bq, bk, bv, relk, biasqkv, relkT, R);

    ln_bf16<<<BSROWS, 256, 0, stream>>>(x, ln1g, ln1b, h1);

    // QKV: [1024,1024] @ [3072,1024]^T -> qkvb bf16 (direct, nt=16)
    gemm128<<<dim3(24, 8, 1), 256, 0, stream>>>(
        h1, WqkvT, nullptr, qkvb, biasqkv,
        ND, ND, ND, 3 * ND,
        0, 0, 1, 0, 0, 1, 0, 1, 0, 0);

    transpose_v<<<dim3(4, 16, NBH), tb, 0, stream>>>(qkvb, vt);

    // qr[bh,i,r] = q . rel_k : per-head A = qkvb col-slice, K=128 (nt=2)
    gemm128<<<dim3(1, 4, NBH), 256, 0, stream>>>(
        qkvb, relkT, qr, nullptr, nullptr,
        NDK, 3 * ND, NDK, QRLD,
        (long)NS * 3 * ND, NDK, NH,
        0, 0, 1,
        (long)NS * QRLD, 1, 0, 0);

    // scores = q @ k^T (per-head col-slices of qkvb, nt=2)
    gemm128<<<dim3(4, 4, NBH), 256, 0, stream>>>(
        qkvb, qkvb + ND, scoresb, nullptr, nullptr,
        NDK, 3 * ND, 3 * ND, NS,
        (long)NS * 3 * ND, NDK, NH,
        (long)NS * 3 * ND, NDK, NH,
        (long)NS * NS, 1, 0, 0);

    softmax_rel<<<dim3(NS, NH, NB), 256, 0, stream>>>(
        scoresb, qr, relation, mask, attnb, attnR, loss_part, sep_p);

    // ctx = attn @ v : split-K x4 (Ksp=128, nt=2), batch 16 -> 256 blocks
    gemm128<<<dim3(1, 4, NBH * 4), 256, 0, stream>>>(
        attnb, vt, ctxPart, nullptr, nullptr,
        128, NS, NS, NDK,
        (long)NS * NS, 0, 1,
        (long)NDK * NS, 0, 1,
        (long)NS * NDK, 4, (long)NBH * NS * NDK, 0);

    ctx_reduce<<<4096, 256, 0, stream>>>(ctxPart, attnR, relvT, ctxm);

    // attn_out partials: ctxm @ Wo, split-K x4 (Ksp=256, nt=4) -> 256 blocks
    gemm128<<<dim3(8, 8, 4), 256, 0, stream>>>(
        ctxm, WoT, woPart, nullptr, nullptr,
        256, ND, ND, ND,
        0, 0, 1, 0, 0, 1,
        0, 4, (long)BSROWS * ND, 0);

    // fused: out = x + bo + sum_4 partials; h2 = LN2(out)
    wo_reduce_ln<<<BSROWS, 256, 0, stream>>>(woPart, x, bo, ln2g, ln2b, out, h2);

    // FFN1: relu(h2 @ W1 + b1) -> F1 bf16 (direct, nt=16)
    gemm128<<<dim3(32, 8, 1), 256, 0, stream>>>(
        h2, W1T, nullptr, F1, b1,
        ND, ND, ND, NDFF,
        0, 0, 1, 0, 0, 1, 0, 1, 0, 1);

    // FFN2 partials: F1 @ W2, split-K x8 (Ksp=512, nt=8) -> 512 blocks
    gemm128<<<dim3(8, 8, 8), 256, 0, stream>>>(
        F1, W2T, f2Part, nullptr, nullptr,
        512, NDFF, NDFF, ND,
        0, 0, 1, 0, 0, 1,
        0, 8, (long)BSROWS * ND, 0);

    ffn2_reduce<<<1024, 256, 0, stream>>>(f2Part, b2, out);

    finalize_loss<<<1, 256, 0, stream>>>(loss_part, hist, sep_p, out_loss);
}

// Round 7
// 165.610 us; speedup vs baseline: 1.3540x; 1.2053x over previous
//
#include <hip/hip_runtime.h>
#include <hip/hip_bf16.h>

#define NB 2
#define NS 512
#define ND 1024
#define NH 8
#define NDK 128
#define NDFF 4096
#define RPAD 64
#define LDSC 640              /* scores row stride: 512 scores + 128 qr */
#define BSROWS 1024           /* B*S */
#define NBH 16                /* B*H */

typedef __bf16 bf16x8 __attribute__((ext_vector_type(8)));
typedef __bf16 bf16x4 __attribute__((ext_vector_type(4)));
typedef float f32x4 __attribute__((ext_vector_type(4)));

#define BM 64
#define BN 64
#define BK 64

__device__ __forceinline__ void gload16(const void* g, void* l) {
    __builtin_amdgcn_global_load_lds(
        (const __attribute__((address_space(1))) void*)g,
        (__attribute__((address_space(3))) void*)l, 16, 0, 0);
}

// ---------------------------------------------------------------------------
// Counted-vmcnt pipelined MFMA GEMM, 64x64 tile, BK=64, 4 waves (each 32x32).
// 2 LDS buffers; 4 loads/wave/tile stay in flight across barriers (vmcnt(4)).
// Both-sides XOR swizzle: global source col pre-swizzled (linear LDS dest),
// ds_read applies the same XOR. Requires nt = Ksp/BK even >= 2.
// flags: 1=relu, 4=fused-rel-B (col tiles >= NS read Brel [128,128]).
// ---------------------------------------------------------------------------
__global__ __launch_bounds__(256, 4) void gemm64(
    const __bf16* __restrict__ A, const __bf16* __restrict__ Bt,
    const __bf16* __restrict__ Brel,
    float* __restrict__ Cf, __bf16* __restrict__ Cb,
    const float* __restrict__ bias,
    int Ksp, int lda, int ldb, int ldc,
    long sA, long sA2, int zdivA,
    long sB, long sB2, int zdivB,
    long sC, int nsplit, long sPart, int flags)
{
    __shared__ __bf16 As0[BM * BK];
    __shared__ __bf16 As1[BM * BK];
    __shared__ __bf16 Bs0[BN * BK];
    __shared__ __bf16 Bs1[BN * BK];

    const int z = blockIdx.z;
    const int bh = z / nsplit, sp = z - bh * nsplit;
    const long kbase = (long)sp * Ksp;
    A  += (long)(bh / zdivA) * sA + (long)(bh % zdivA) * sA2 + kbase;
    Bt += (long)(bh / zdivB) * sB + (long)(bh % zdivB) * sB2 + kbase;
    const long cbase = (long)bh * sC + (long)sp * sPart;

    const int tM = blockIdx.y * BM, tN = blockIdx.x * BN;
    const int t = threadIdx.x, lane = t & 63, w = t >> 6;
    const int wr = w >> 1, wc = w & 1;

    // B source select (fused qr tiles read relkT, no z-offset, K=128 rows)
    const __bf16* Bbase = Bt;
    int ldbx = ldb, tNB = tN;
    if ((flags & 4) && tN >= NS) { Bbase = Brel + kbase; ldbx = 128; tNB = tN - NS; }

    // staging: row = lane>>3 within 8-row chunk; source col pre-swizzled so
    // linear LDS ends up row-XOR-swizzled: c_src = c_lds ^ ((row&7)<<4) bytes
    const int srow = lane >> 3;
    const int scolE = ((((lane & 7) << 4) ^ (srow << 4)) >> 1);

    const __bf16* gA = A + (long)(tM + srow) * lda + scolE;
    const __bf16* gB = Bbase + (long)(tNB + srow) * ldbx + scolE;

    f32x4 acc[2][2];
#pragma unroll
    for (int m = 0; m < 2; ++m)
#pragma unroll
        for (int n = 0; n < 2; ++n)
#pragma unroll
            for (int j = 0; j < 4; ++j) acc[m][n][j] = 0.f;

    const int r16 = lane & 15;
    const int kq = (lane >> 4) * 8;
    const int xorE = (r16 & 7) * 8;
    const int nt = Ksp / BK;

    auto STAGE = [&](__bf16* as, __bf16* bs, int k0) {
#pragma unroll
        for (int i = 0; i < 2; ++i) {
            const int rr = (w + i * 4) * 8;   // wave-uniform 8-row chunk base
            gload16(gA + (long)rr * lda + k0, (void*)&as[rr * BK]);
            gload16(gB + (long)rr * ldbx + k0, (void*)&bs[rr * BK]);
        }
    };
    auto COMPUTE = [&](const __bf16* as, const __bf16* bs) {
#pragma unroll
        for (int ks = 0; ks < 2; ++ks) {
            bf16x8 af[2], bv[2];
#pragma unroll
            for (int m = 0; m < 2; ++m)
                af[m] = *(const bf16x8*)&as[(wr * 32 + m * 16 + r16) * BK + ((ks * 32 + kq) ^ xorE)];
#pragma unroll
            for (int n = 0; n < 2; ++n)
                bv[n] = *(const bf16x8*)&bs[(wc * 32 + n * 16 + r16) * BK + ((ks * 32 + kq) ^ xorE)];
#pragma unroll
            for (int m = 0; m < 2; ++m)
#pragma unroll
                for (int n = 0; n < 2; ++n)
                    acc[m][n] = __builtin_amdgcn_mfma_f32_16x16x32_bf16(af[m], bv[n], acc[m][n], 0, 0, 0);
        }
    };

    STAGE(As0, Bs0, 0);        // 4 loads/wave
    STAGE(As1, Bs1, BK);       // 8 in flight
    for (int tt = 0; tt < nt; tt += 2) {
        asm volatile("s_waitcnt vmcnt(4)\n\ts_barrier" ::: "memory");   // buf0 ready
        COMPUTE(As0, Bs0);
        asm volatile("s_waitcnt lgkmcnt(0)\n\ts_barrier" ::: "memory");
        const bool more = (tt + 2 < nt);
        if (more) {
            STAGE(As0, Bs0, (tt + 2) * BK);
            asm volatile("s_waitcnt vmcnt(4)\n\ts_barrier" ::: "memory"); // buf1 ready
        } else {
            asm volatile("s_waitcnt vmcnt(0)\n\ts_barrier" ::: "memory");
        }
        COMPUTE(As1, Bs1);
        asm volatile("s_waitcnt lgkmcnt(0)\n\ts_barrier" ::: "memory");
        if (more) STAGE(As1, Bs1, (tt + 3) * BK);
    }

    const bool relu = (flags & 1) != 0;
#pragma unroll
    for (int m = 0; m < 2; ++m) {
        const int gr0 = tM + wr * 32 + m * 16 + (lane >> 4) * 4;
#pragma unroll
        for (int n = 0; n < 2; ++n) {
            const int gc = tN + wc * 32 + n * 16 + (lane & 15);
            const float bb = bias ? bias[gc] : 0.f;
#pragma unroll
            for (int j = 0; j < 4; ++j) {
                float v = acc[m][n][j] + bb;
                if (relu) v = fmaxf(v, 0.f);
                const long idx = cbase + (long)(gr0 + j) * ldc + gc;
                if (Cb) Cb[idx] = (__bf16)v;
                else Cf[idx] = v;
            }
        }
    }
}

// ---------------------------------------------------------------------------
// LayerNorm over D=1024, one block/row, bf16 out. (LN1)
// ---------------------------------------------------------------------------
__global__ __launch_bounds__(256) void ln_bf16(
    const float* __restrict__ x, const float* __restrict__ g,
    const float* __restrict__ bb, __bf16* __restrict__ out)
{
    const long row = blockIdx.x;
    const float* xr = x + row * ND;
    __bf16* orow = out + row * ND;
    const int t = threadIdx.x;
    float4 v = reinterpret_cast<const float4*>(xr)[t];
    float s = v.x + v.y + v.z + v.w;
    float s2 = v.x * v.x + v.y * v.y + v.z * v.z + v.w * v.w;
#pragma unroll
    for (int o = 32; o > 0; o >>= 1) {
        s += __shfl_xor(s, o, 64);
        s2 += __shfl_xor(s2, o, 64);
    }
    __shared__ float red[8];
    const int lane = t & 63, wv = t >> 6;
    if (lane == 0) { red[wv] = s; red[4 + wv] = s2; }
    __syncthreads();
    s = red[0] + red[1] + red[2] + red[3];
    s2 = red[4] + red[5] + red[6] + red[7];
    const float mean = s * (1.f / ND);
    const float var = s2 * (1.f / ND) - mean * mean;
    const float rs = rsqrtf(var + 1e-5f);
    const float xv[4] = {v.x, v.y, v.z, v.w};
    bf16x4 o;
#pragma unroll
    for (int j = 0; j < 4; ++j) {
        const int c = t * 4 + j;
        o[j] = (__bf16)((xv[j] - mean) * rs * g[c] + bb[c]);
    }
    *(bf16x4*)&orow[t * 4] = o;
}

// ---------------------------------------------------------------------------
// Fused weight prep: all fp32->bf16 transposes in one launch.
// ---------------------------------------------------------------------------
__global__ void prep_weights(
    const float* __restrict__ Wq, const float* __restrict__ Wk,
    const float* __restrict__ Wv, const float* __restrict__ Wo,
    const float* __restrict__ W1, const float* __restrict__ W2,
    const float* __restrict__ relv,
    __bf16* __restrict__ WqkvT, __bf16* __restrict__ WoT,
    __bf16* __restrict__ W1T, __bf16* __restrict__ W2T,
    __bf16* __restrict__ relvT, int R)
{
    const int tile = blockIdx.x;
    const float* src; __bf16* dst;
    int rows_in, cols_in, ldo, kx, ny;
    if (tile < 4096) {
        const int m = tile >> 10, r = tile & 1023;
        kx = r & 31; ny = r >> 5;
        rows_in = 1024; cols_in = 1024; ldo = 1024;
        src = m == 0 ? Wq : m == 1 ? Wk : m == 2 ? Wv : Wo;
        dst = m == 3 ? WoT : WqkvT + (size_t)m * 1024 * 1024;
    } else if (tile < 8192) {
        const int r = tile - 4096;
        kx = r & 31; ny = r >> 5;
        rows_in = 1024; cols_in = 4096; ldo = 1024; src = W1; dst = W1T;
    } else if (tile < 12288) {
        const int r = tile - 8192;
        kx = r & 127; ny = r >> 7;
        rows_in = 4096; cols_in = 1024; ldo = 4096; src = W2; dst = W2T;
    } else {
        const int r = tile - 12288;
        kx = r & 1; ny = r >> 1;
        rows_in = R; cols_in = 128; ldo = 64; src = relv; dst = relvT;
    }

    __shared__ float tl[32][33];
    const int k0 = kx * 32, n0 = ny * 32;
    const int tx = threadIdx.x, ty = threadIdx.y;
#pragma unroll
    for (int dy = 0; dy < 32; dy += 8) {
        const int k = k0 + ty + dy, n = n0 + tx;
        tl[ty + dy][tx] = (k < rows_in && n < cols_in) ? src[(long)k * cols_in + n] : 0.f;
    }
    __syncthreads();
#pragma unroll
    for (int dy = 0; dy < 32; dy += 8) {
        const int n = n0 + ty + dy, k = k0 + tx;
        if (n < cols_in && k < ldo) dst[(long)n * ldo + k] = (__bf16)tl[tx][ty + dy];
    }
}

// pack_bias + relk pad in one launch (grid 76 x 256)
__global__ void prep_small(const float* __restrict__ bq, const float* __restrict__ bk,
                           const float* __restrict__ bv, const float* __restrict__ relk,
                           float* __restrict__ biasqkv, __bf16* __restrict__ relkT, int R)
{
    const int t = blockIdx.x * 256 + threadIdx.x;
    if (t < ND) biasqkv[t] = bq[t];
    else if (t < 2 * ND) biasqkv[t] = bk[t - ND];
    else if (t < 3 * ND) biasqkv[t] = bv[t - 2 * ND];
    else {
        const int idx = t - 3 * ND;
        if (idx < 128 * NDK) {
            const int r = idx / NDK;
            relkT[idx] = (r < R) ? (__bf16)relk[idx] : (__bf16)0.f;
        }
    }
}

// V slice of packed qkvb [1024,3072] -> vt [B,H,DK,S] bf16
__global__ void transpose_v(const __bf16* __restrict__ qkvb, __bf16* __restrict__ vt)
{
    __shared__ __bf16 tile[32][33];
    const int bh = blockIdx.z, b = bh >> 3, h = bh & 7;
    const int d0 = blockIdx.x * 32, i0 = blockIdx.y * 32;
    const int tx = threadIdx.x, ty = threadIdx.y;
    const __bf16* src = qkvb + 2 * ND + h * NDK;
#pragma unroll
    for (int dy = 0; dy < 32; dy += 8)
        tile[ty + dy][tx] = src[(long)(b * NS + i0 + ty + dy) * (3 * ND) + d0 + tx];
    __syncthreads();
#pragma unroll
    for (int dy = 0; dy < 32; dy += 8)
        vt[((long)bh * NDK + d0 + ty + dy) * NS + i0 + tx] = tile[tx][ty + dy];
}

// ---------------------------------------------------------------------------
// Fused softmax + relation gather + attnR binning + history-loss partial.
// scores rows are LDSC=640 wide: cols [0,512) = qk, [512,640) = qr table.
// ---------------------------------------------------------------------------
__global__ __launch_bounds__(256) void softmax_rel(
    const float* __restrict__ scores,
    const int* __restrict__ relation, const int* __restrict__ mask,
    __bf16* __restrict__ attn, __bf16* __restrict__ attnR,
    float* __restrict__ loss_part, const int* __restrict__ sep_p)
{
    const int i = blockIdx.x, h = blockIdx.y, b = blockIdx.z;
    const long bh = (long)(b * NH + h);
    const float* srow = scores + (bh * NS + i) * LDSC;
    const int* rrow = relation + ((long)b * NS + i) * NS;
    const int* mrow = mask + ((long)b * NS + i) * NS;
    __bf16* arow = attn + (bh * NS + i) * NS;
    __bf16* aRrow = attnR + (bh * NS + i) * RPAD;

    __shared__ float qrl[RPAD];
    __shared__ float bins[RPAD];
    __shared__ float red[4];

    const int t = threadIdx.x;
    const float s0 = srow[t], s1 = srow[t + 256];
    const int r0 = rrow[t], r1 = rrow[t + 256];
    const int m0 = mrow[t], m1 = mrow[t + 256];
    if (t < RPAD) { qrl[t] = srow[NS + t]; bins[t] = 0.f; }
    __syncthreads();

    const float sc = 0.088388347648318447f;  // 1/sqrt(128)
    float v0 = (s0 + qrl[r0]) * sc;
    float v1 = (s1 + qrl[r1]) * sc;
    if (m0 == 0) v0 = -1e9f;
    if (m1 == 0) v1 = -1e9f;

    const int lane = t & 63, wv = t >> 6;

    float mx = fmaxf(v0, v1);
#pragma unroll
    for (int o = 32; o > 0; o >>= 1) mx = fmaxf(mx, __shfl_xor(mx, o, 64));
    if (lane == 0) red[wv] = mx;
    __syncthreads();
    mx = fmaxf(fmaxf(red[0], red[1]), fmaxf(red[2], red[3]));
    __syncthreads();

    const float e0 = __expf(v0 - mx), e1 = __expf(v1 - mx);
    float sm = e0 + e1;
#pragma unroll
    for (int o = 32; o > 0; o >>= 1) sm += __shfl_xor(sm, o, 64);
    if (lane == 0) red[wv] = sm;
    __syncthreads();
    sm = red[0] + red[1] + red[2] + red[3];
    __syncthreads();

    const float inv = 1.f / sm;
    const float a0 = e0 * inv, a1 = e1 * inv;
    arow[t] = (__bf16)a0;
    arow[t + 256] = (__bf16)a1;
    atomicAdd(&bins[r0], a0);
    atomicAdd(&bins[r1], a1);

    const int sep = *sep_p;
    float ls = 0.f;
    if (t < sep) ls += a0;
    if (t + 256 < sep) ls += a1;
#pragma unroll
    for (int o = 32; o > 0; o >>= 1) ls += __shfl_xor(ls, o, 64);
    if (lane == 0) red[wv] = ls;
    __syncthreads();  // also fences bins atomics
    if (t == 0) loss_part[bh * NS + i] = red[0] + red[1] + red[2] + red[3];
    if (t < RPAD) aRrow[t] = (__bf16)bins[t];
}

// ctx split-K(2) reduce + fused attnR@rel_v + merge_heads -> ctxm bf16 [B*S, D]
__global__ __launch_bounds__(256) void ctx_reduce(
    const float* __restrict__ P, const __bf16* __restrict__ attnR,
    const __bf16* __restrict__ relvT, __bf16* __restrict__ ctxm)
{
    const int idx = blockIdx.x * 256 + threadIdx.x;  // bh*65536 + i*128 + d
    const int d = idx & 127;
    const int i = (idx >> 7) & 511;
    const int h = (idx >> 16) & 7;
    const int b = idx >> 19;
    const long sP = (long)NBH * NS * NDK;
    float s = P[idx] + P[idx + sP];

    const bf16x8* ar = (const bf16x8*)(attnR + ((long)(idx >> 16) * NS + i) * RPAD);
    const bf16x8* rv = (const bf16x8*)(relvT + (long)d * RPAD);
    float acc = 0.f;
#pragma unroll
    for (int q = 0; q < 8; ++q) {
        bf16x8 a = ar[q], vv = rv[q];
#pragma unroll
        for (int j = 0; j < 8; ++j) acc += (float)a[j] * (float)vv[j];
    }
    ctxm[((long)(b * NS + i)) * ND + h * NDK + d] = (__bf16)(s + acc);
}

// Wo split-K(2) reduce + residual + bias, fused LN2 -> out fp32 + h2 bf16.
__global__ __launch_bounds__(256) void wo_reduce_ln(
    const float* __restrict__ P, const float* __restrict__ x,
    const float* __restrict__ bo, const float* __restrict__ g,
    const float* __restrict__ bb, float* __restrict__ out,
    __bf16* __restrict__ h2)
{
    const int row = blockIdx.x;
    const int t = threadIdx.x;
    const long i4 = (long)row * 256 + t;
    const long sP = (long)BSROWS * ND / 4;
    const float4* P4 = (const float4*)P;
    float4 s = P4[i4];
    const float4 t1 = P4[i4 + sP];
    s.x += t1.x; s.y += t1.y; s.z += t1.z; s.w += t1.w;
    const int col = t * 4;
    const float4 xv = ((const float4*)x)[i4];
    const float4 bv = *(const float4*)&bo[col];
    float4 o;
    o.x = s.x + xv.x + bv.x; o.y = s.y + xv.y + bv.y;
    o.z = s.z + xv.z + bv.z; o.w = s.w + xv.w + bv.w;
    ((float4*)out)[i4] = o;

    float sum = o.x + o.y + o.z + o.w;
    float sum2 = o.x * o.x + o.y * o.y + o.z * o.z + o.w * o.w;
#pragma unroll
    for (int of = 32; of > 0; of >>= 1) {
        sum += __shfl_xor(sum, of, 64);
        sum2 += __shfl_xor(sum2, of, 64);
    }
    __shared__ float red[8];
    const int lane = t & 63, wv = t >> 6;
    if (lane == 0) { red[wv] = sum; red[4 + wv] = sum2; }
    __syncthreads();
    sum = red[0] + red[1] + red[2] + red[3];
    sum2 = red[4] + red[5] + red[6] + red[7];
    const float mean = sum * (1.f / ND);
    const float var = sum2 * (1.f / ND) - mean * mean;
    const float rs = rsqrtf(var + 1e-5f);
    const float ov[4] = {o.x, o.y, o.z, o.w};
    bf16x4 hb;
#pragma unroll
    for (int j = 0; j < 4; ++j)
        hb[j] = (__bf16)((ov[j] - mean) * rs * g[col + j] + bb[col + j]);
    *(bf16x4*)&h2[(long)row * ND + col] = hb;
}

// FFN2 split-K(4) reduce: out += b2 + sum_4 partials
__global__ __launch_bounds__(256) void ffn2_reduce(
    const float* __restrict__ P, const float* __restrict__ b2, float* __restrict__ out)
{
    const int i4 = blockIdx.x * 256 + threadIdx.x;
    const long sP = (long)BSROWS * ND / 4;
    const float4* P4 = (const float4*)P;
    float4 s = P4[i4];
#pragma unroll
    for (int sp = 1; sp < 4; ++sp) {
        const float4 t = P4[i4 + sp * sP];
        s.x += t.x; s.y += t.y; s.z += t.z; s.w += t.w;
    }
    const int col = (i4 * 4) & (ND - 1);
    const float4 bv = *(const float4*)&b2[col];
    float4 o = ((float4*)out)[i4];
    o.x += s.x + bv.x; o.y += s.y + bv.y;
    o.z += s.z + bv.z; o.w += s.w + bv.w;
    ((float4*)out)[i4] = o;
}

// Reduce 8192 per-row loss partials in one block.
__global__ __launch_bounds__(256) void finalize_loss(
    const float* __restrict__ loss_part, const float* __restrict__ hist,
    const int* __restrict__ sep_p, float* __restrict__ out_loss)
{
    const int t = threadIdx.x;
    float s = 0.f;
#pragma unroll
    for (int k = 0; k < NBH * NS / 1024; ++k) {
        const float4 v = ((const float4*)loss_part)[t + k * 256];
        s += v.x + v.y + v.z + v.w;
    }
#pragma unroll
    for (int o = 32; o > 0; o >>= 1) s += __shfl_xor(s, o, 64);
    __shared__ float red[4];
    if ((t & 63) == 0) red[t >> 6] = s;
    __syncthreads();
    if (t == 0) {
        const int sep = *sep_p;
        const float total = red[0] + red[1] + red[2] + red[3];
        const float denom = (float)NB * NH * NS * (float)(sep > 0 ? sep : 1);
        out_loss[0] = (sep > 0) ? hist[0] * total / denom : 0.f;
    }
}

// ---------------------------------------------------------------------------
static inline int cdiv(int a, int b) { return (a + b - 1) / b; }

extern "C" void kernel_launch(void* const* d_in, const int* in_sizes, int n_in,
                              void* d_out, int out_size, void* d_ws, size_t ws_size,
                              hipStream_t stream)
{
    const float* x      = (const float*)d_in[0];
    const int* relation = (const int*)d_in[1];
    const int* mask     = (const int*)d_in[2];
    const int* sep_p    = (const int*)d_in[3];
    const float* hist   = (const float*)d_in[4];
    const float* Wq = (const float*)d_in[5],  *bq = (const float*)d_in[6];
    const float* Wk = (const float*)d_in[7],  *bk = (const float*)d_in[8];
    const float* Wv = (const float*)d_in[9],  *bv = (const float*)d_in[10];
    const float* Wo = (const float*)d_in[11], *bo = (const float*)d_in[12];
    const float* relk = (const float*)d_in[13];
    const float* relv = (const float*)d_in[14];
    const float* ln1g = (const float*)d_in[15], *ln1b = (const float*)d_in[16];
    const float* ln2g = (const float*)d_in[17], *ln2b = (const float*)d_in[18];
    const float* W1 = (const float*)d_in[19], *b1 = (const float*)d_in[20];
    const float* W2 = (const float*)d_in[21], *b2 = (const float*)d_in[22];
    const int R = in_sizes[13] / NDK;  // 51

    float* out = (float*)d_out;
    float* out_loss = out + (long)BSROWS * ND;

    char* p = (char*)d_ws;
    auto alloc = [&](size_t bytes) -> void* {
        void* r = (void*)p;
        p += (bytes + 255) & ~(size_t)255;
        return r;
    };
    __bf16* WqkvT   = (__bf16*)alloc((size_t)3 * ND * ND * 2);
    __bf16* WoT     = (__bf16*)alloc((size_t)ND * ND * 2);
    __bf16* W1T     = (__bf16*)alloc((size_t)NDFF * ND * 2);
    __bf16* W2T     = (__bf16*)alloc((size_t)ND * NDFF * 2);
    __bf16* relkT   = (__bf16*)alloc((size_t)128 * NDK * 2);
    __bf16* relvT   = (__bf16*)alloc((size_t)NDK * RPAD * 2);
    float*  biasqkv = (float*)alloc((size_t)3 * ND * 4);
    __bf16* h1      = (__bf16*)alloc((size_t)BSROWS * ND * 2);
    __bf16* qkvb    = (__bf16*)alloc((size_t)BSROWS * 3 * ND * 2);
    __bf16* vt      = (__bf16*)alloc((size_t)NBH * NDK * NS * 2);
    __bf16* attnb   = (__bf16*)alloc((size_t)NBH * NS * NS * 2);
    __bf16* attnR   = (__bf16*)alloc((size_t)NBH * NS * RPAD * 2);
    __bf16* ctxm    = (__bf16*)alloc((size_t)BSROWS * ND * 2);
    __bf16* h2      = (__bf16*)alloc((size_t)BSROWS * ND * 2);
    __bf16* F1      = (__bf16*)alloc((size_t)BSROWS * NDFF * 2);
    float*  loss_part = (float*)alloc((size_t)NBH * NS * 4);
    float*  arena   = (float*)alloc((size_t)64 * 1024 * 1024);
    // arena aliasing (lifetimes disjoint), offsets in floats:
    float* scoresb = arena;                            // 21MB [0,21) dead after softmax
    float* ctxPart = arena + (size_t)6 * 1024 * 1024;  // 8MB [24,32)
    float* woPart  = arena;                            // 8MB [0,8)
    float* f2Part  = arena + (size_t)2 * 1024 * 1024;  // 16MB [8,24)

    const dim3 tb(32, 8);
    prep_weights<<<12296, tb, 0, stream>>>(Wq, Wk, Wv, Wo, W1, W2, relv,
                                           WqkvT, WoT, W1T, W2T, relvT, R);
    prep_small<<<76, 256, 0, stream>>>(bq, bk, bv, relk, biasqkv, relkT, R);

    ln_bf16<<<BSROWS, 256, 0, stream>>>(x, ln1g, ln1b, h1);

    // QKV: [1024,1024] @ [3072,1024]^T -> qkvb bf16 (768 blocks, nt=16)
    gemm64<<<dim3(48, 16, 1), 256, 0, stream>>>(
        h1, WqkvT, nullptr, nullptr, qkvb, biasqkv,
        ND, ND, ND, 3 * ND,
        0, 0, 1, 0, 0, 1, 0, 1, 0, 0);

    transpose_v<<<dim3(4, 16, NBH), tb, 0, stream>>>(qkvb, vt);

    // scores+qr fused: per-head q @ [k^T | relk^T] -> scoresb [512,640]
    // (1280 blocks, nt=2; col tiles >= 512 read relkT via flags|4)
    gemm64<<<dim3(10, 8, NBH), 256, 0, stream>>>(
        qkvb, qkvb + ND, relkT, scoresb, nullptr, nullptr,
        NDK, 3 * ND, 3 * ND, LDSC,
        (long)NS * 3 * ND, NDK, NH,
        (long)NS * 3 * ND, NDK, NH,
        (long)NS * LDSC, 1, 0, 4);

    softmax_rel<<<dim3(NS, NH, NB), 256, 0, stream>>>(
        scoresb, relation, mask, attnb, attnR, loss_part, sep_p);

    // ctx = attn @ v : split-K x2 (Ksp=256, nt=4), 512 blocks
    gemm64<<<dim3(2, 8, NBH * 2), 256, 0, stream>>>(
        attnb, vt, nullptr, ctxPart, nullptr, nullptr,
        256, NS, NS, NDK,
        (long)NS * NS, 0, 1,
        (long)NDK * NS, 0, 1,
        (long)NS * NDK, 2, (long)NBH * NS * NDK, 0);

    ctx_reduce<<<4096, 256, 0, stream>>>(ctxPart, attnR, relvT, ctxm);

    // attn_out partials: ctxm @ Wo, split-K x2 (Ksp=512, nt=8), 512 blocks
    gemm64<<<dim3(16, 16, 2), 256, 0, stream>>>(
        ctxm, WoT, nullptr, woPart, nullptr, nullptr,
        512, ND, ND, ND,
        0, 0, 1, 0, 0, 1,
        0, 2, (long)BSROWS * ND, 0);

    // fused: out = x + bo + sum_2 partials; h2 = LN2(out)
    wo_reduce_ln<<<BSROWS, 256, 0, stream>>>(woPart, x, bo, ln2g, ln2b, out, h2);

    // FFN1: relu(h2 @ W1 + b1) -> F1 bf16 (1024 blocks, nt=16)
    gemm64<<<dim3(64, 16, 1), 256, 0, stream>>>(
        h2, W1T, nullptr, nullptr, F1, b1,
        ND, ND, ND, NDFF,
        0, 0, 1, 0, 0, 1, 0, 1, 0, 1);

    // FFN2 partials: F1 @ W2, split-K x4 (Ksp=1024, nt=16), 1024 blocks
    gemm64<<<dim3(16, 16, 4), 256, 0, stream>>>(
        F1, W2T, nullptr, f2Part, nullptr, nullptr,
        1024, NDFF, NDFF, ND,
        0, 0, 1, 0, 0, 1,
        0, 4, (long)BSROWS * ND, 0);

    ffn2_reduce<<<1024, 256, 0, stream>>>(f2Part, b2, out);

    finalize_loss<<<1, 256, 0, stream>>>(loss_part, hist, sep_p, out_loss);
}

// Round 8
// 162.723 us; speedup vs baseline: 1.3780x; 1.0177x over previous
//
#include <hip/hip_runtime.h>
#include <hip/hip_bf16.h>

#define NB 2
#define NS 512
#define ND 1024
#define NH 8
#define NDK 128
#define NDFF 4096
#define RPAD 64
#define LDSC 640              /* scores row stride: 512 scores + 128 qr */
#define BSROWS 1024           /* B*S */
#define NBH 16                /* B*H */

typedef __bf16 bf16x8 __attribute__((ext_vector_type(8)));
typedef __bf16 bf16x4 __attribute__((ext_vector_type(4)));
typedef float f32x4 __attribute__((ext_vector_type(4)));

#define BM 64
#define BN 64
#define BK 64

__device__ __forceinline__ void gload16(const void* g, void* l) {
    __builtin_amdgcn_global_load_lds(
        (const __attribute__((address_space(1))) void*)g,
        (__attribute__((address_space(3))) void*)l, 16, 0, 0);
}

// ---------------------------------------------------------------------------
// Counted-vmcnt pipelined MFMA GEMM, 64x64 tile, BK=64, 4 waves (each 32x32).
// 2 LDS buffers; loads stay in flight across barriers (vmcnt(4)).
// Both-sides XOR swizzle. Requires nt = Ksp/BK even >= 2.
// flags: 1=relu, 4=fused-rel-B (col tiles >= NS read Brel [128,128]).
// ---------------------------------------------------------------------------
__global__ __launch_bounds__(256, 4) void gemm64(
    const __bf16* __restrict__ A, const __bf16* __restrict__ Bt,
    const __bf16* __restrict__ Brel,
    float* __restrict__ Cf, __bf16* __restrict__ Cb,
    const float* __restrict__ bias,
    int Ksp, int lda, int ldb, int ldc,
    long sA, long sA2, int zdivA,
    long sB, long sB2, int zdivB,
    long sC, int nsplit, long sPart, int flags)
{
    __shared__ __bf16 As0[BM * BK];
    __shared__ __bf16 As1[BM * BK];
    __shared__ __bf16 Bs0[BN * BK];
    __shared__ __bf16 Bs1[BN * BK];

    const int z = blockIdx.z;
    const int bh = z / nsplit, sp = z - bh * nsplit;
    const long kbase = (long)sp * Ksp;
    A  += (long)(bh / zdivA) * sA + (long)(bh % zdivA) * sA2 + kbase;
    Bt += (long)(bh / zdivB) * sB + (long)(bh % zdivB) * sB2 + kbase;
    const long cbase = (long)bh * sC + (long)sp * sPart;

    const int tM = blockIdx.y * BM, tN = blockIdx.x * BN;
    const int t = threadIdx.x, lane = t & 63, w = t >> 6;
    const int wr = w >> 1, wc = w & 1;

    const __bf16* Bbase = Bt;
    int ldbx = ldb, tNB = tN;
    if ((flags & 4) && tN >= NS) { Bbase = Brel + kbase; ldbx = 128; tNB = tN - NS; }

    const int srow = lane >> 3;
    const int scolE = ((((lane & 7) << 4) ^ (srow << 4)) >> 1);

    const __bf16* gA = A + (long)(tM + srow) * lda + scolE;
    const __bf16* gB = Bbase + (long)(tNB + srow) * ldbx + scolE;

    f32x4 acc[2][2];
#pragma unroll
    for (int m = 0; m < 2; ++m)
#pragma unroll
        for (int n = 0; n < 2; ++n)
#pragma unroll
            for (int j = 0; j < 4; ++j) acc[m][n][j] = 0.f;

    const int r16 = lane & 15;
    const int kq = (lane >> 4) * 8;
    const int xorE = (r16 & 7) * 8;
    const int nt = Ksp / BK;

    auto STAGE = [&](__bf16* as, __bf16* bs, int k0) {
#pragma unroll
        for (int i = 0; i < 2; ++i) {
            const int rr = (w + i * 4) * 8;
            gload16(gA + (long)rr * lda + k0, (void*)&as[rr * BK]);
            gload16(gB + (long)rr * ldbx + k0, (void*)&bs[rr * BK]);
        }
    };
    auto COMPUTE = [&](const __bf16* as, const __bf16* bs) {
#pragma unroll
        for (int ks = 0; ks < 2; ++ks) {
            bf16x8 af[2], bv[2];
#pragma unroll
            for (int m = 0; m < 2; ++m)
                af[m] = *(const bf16x8*)&as[(wr * 32 + m * 16 + r16) * BK + ((ks * 32 + kq) ^ xorE)];
#pragma unroll
            for (int n = 0; n < 2; ++n)
                bv[n] = *(const bf16x8*)&bs[(wc * 32 + n * 16 + r16) * BK + ((ks * 32 + kq) ^ xorE)];
#pragma unroll
            for (int m = 0; m < 2; ++m)
#pragma unroll
                for (int n = 0; n < 2; ++n)
                    acc[m][n] = __builtin_amdgcn_mfma_f32_16x16x32_bf16(af[m], bv[n], acc[m][n], 0, 0, 0);
        }
    };

    STAGE(As0, Bs0, 0);
    STAGE(As1, Bs1, BK);
    for (int tt = 0; tt < nt; tt += 2) {
        asm volatile("s_waitcnt vmcnt(4)\n\ts_barrier" ::: "memory");
        COMPUTE(As0, Bs0);
        asm volatile("s_waitcnt lgkmcnt(0)\n\ts_barrier" ::: "memory");
        const bool more = (tt + 2 < nt);
        if (more) {
            STAGE(As0, Bs0, (tt + 2) * BK);
            asm volatile("s_waitcnt vmcnt(4)\n\ts_barrier" ::: "memory");
        } else {
            asm volatile("s_waitcnt vmcnt(0)\n\ts_barrier" ::: "memory");
        }
        COMPUTE(As1, Bs1);
        asm volatile("s_waitcnt lgkmcnt(0)\n\ts_barrier" ::: "memory");
        if (more) STAGE(As1, Bs1, (tt + 3) * BK);
    }

    const bool relu = (flags & 1) != 0;
#pragma unroll
    for (int m = 0; m < 2; ++m) {
        const int gr0 = tM + wr * 32 + m * 16 + (lane >> 4) * 4;
#pragma unroll
        for (int n = 0; n < 2; ++n) {
            const int gc = tN + wc * 32 + n * 16 + (lane & 15);
            const float bb = bias ? bias[gc] : 0.f;
#pragma unroll
            for (int j = 0; j < 4; ++j) {
                float v = acc[m][n][j] + bb;
                if (relu) v = fmaxf(v, 0.f);
                const long idx = cbase + (long)(gr0 + j) * ldc + gc;
                if (Cb) Cb[idx] = (__bf16)v;
                else Cf[idx] = v;
            }
        }
    }
}

// ---------------------------------------------------------------------------
// LayerNorm over D=1024, one block/row, bf16 out. (LN1)
// ---------------------------------------------------------------------------
__global__ __launch_bounds__(256) void ln_bf16(
    const float* __restrict__ x, const float* __restrict__ g,
    const float* __restrict__ bb, __bf16* __restrict__ out)
{
    const long row = blockIdx.x;
    const float* xr = x + row * ND;
    __bf16* orow = out + row * ND;
    const int t = threadIdx.x;
    float4 v = reinterpret_cast<const float4*>(xr)[t];
    float s = v.x + v.y + v.z + v.w;
    float s2 = v.x * v.x + v.y * v.y + v.z * v.z + v.w * v.w;
#pragma unroll
    for (int o = 32; o > 0; o >>= 1) {
        s += __shfl_xor(s, o, 64);
        s2 += __shfl_xor(s2, o, 64);
    }
    __shared__ float red[8];
    const int lane = t & 63, wv = t >> 6;
    if (lane == 0) { red[wv] = s; red[4 + wv] = s2; }
    __syncthreads();
    s = red[0] + red[1] + red[2] + red[3];
    s2 = red[4] + red[5] + red[6] + red[7];
    const float mean = s * (1.f / ND);
    const float var = s2 * (1.f / ND) - mean * mean;
    const float rs = rsqrtf(var + 1e-5f);
    const float xv[4] = {v.x, v.y, v.z, v.w};
    bf16x4 o;
#pragma unroll
    for (int j = 0; j < 4; ++j) {
        const int c = t * 4 + j;
        o[j] = (__bf16)((xv[j] - mean) * rs * g[c] + bb[c]);
    }
    *(bf16x4*)&orow[t * 4] = o;
}

// ---------------------------------------------------------------------------
// Fused weight prep: all fp32->bf16 transposes + bias pack + relk pad.
// grid.x = 12372 blocks of (32,8).
// ---------------------------------------------------------------------------
__global__ void prep_weights(
    const float* __restrict__ Wq, const float* __restrict__ Wk,
    const float* __restrict__ Wv, const float* __restrict__ Wo,
    const float* __restrict__ W1, const float* __restrict__ W2,
    const float* __restrict__ relv,
    const float* __restrict__ bq, const float* __restrict__ bk,
    const float* __restrict__ bv, const float* __restrict__ relk,
    __bf16* __restrict__ WqkvT, __bf16* __restrict__ WoT,
    __bf16* __restrict__ W1T, __bf16* __restrict__ W2T,
    __bf16* __restrict__ relvT, float* __restrict__ biasqkv,
    __bf16* __restrict__ relkT, int R)
{
    const int tile = blockIdx.x;
    if (tile >= 12296) {   // bias pack + relk pad (flat)
        const int ft = (tile - 12296) * 256 + threadIdx.y * 32 + threadIdx.x;
        if (ft < ND) biasqkv[ft] = bq[ft];
        else if (ft < 2 * ND) biasqkv[ft] = bk[ft - ND];
        else if (ft < 3 * ND) biasqkv[ft] = bv[ft - 2 * ND];
        else {
            const int idx = ft - 3 * ND;
            if (idx < 128 * NDK) {
                const int r = idx / NDK;
                relkT[idx] = (r < R) ? (__bf16)relk[idx] : (__bf16)0.f;
            }
        }
        return;
    }
    const float* src; __bf16* dst;
    int rows_in, cols_in, ldo, kx, ny;
    if (tile < 4096) {
        const int m = tile >> 10, r = tile & 1023;
        kx = r & 31; ny = r >> 5;
        rows_in = 1024; cols_in = 1024; ldo = 1024;
        src = m == 0 ? Wq : m == 1 ? Wk : m == 2 ? Wv : Wo;
        dst = m == 3 ? WoT : WqkvT + (size_t)m * 1024 * 1024;
    } else if (tile < 8192) {
        const int r = tile - 4096;
        kx = r & 31; ny = r >> 5;
        rows_in = 1024; cols_in = 4096; ldo = 1024; src = W1; dst = W1T;
    } else if (tile < 12288) {
        const int r = tile - 8192;
        kx = r & 127; ny = r >> 7;
        rows_in = 4096; cols_in = 1024; ldo = 4096; src = W2; dst = W2T;
    } else {
        const int r = tile - 12288;
        kx = r & 1; ny = r >> 1;
        rows_in = R; cols_in = 128; ldo = 64; src = relv; dst = relvT;
    }

    __shared__ float tl[32][33];
    const int k0 = kx * 32, n0 = ny * 32;
    const int tx = threadIdx.x, ty = threadIdx.y;
#pragma unroll
    for (int dy = 0; dy < 32; dy += 8) {
        const int k = k0 + ty + dy, n = n0 + tx;
        tl[ty + dy][tx] = (k < rows_in && n < cols_in) ? src[(long)k * cols_in + n] : 0.f;
    }
    __syncthreads();
#pragma unroll
    for (int dy = 0; dy < 32; dy += 8) {
        const int n = n0 + ty + dy, k = k0 + tx;
        if (n < cols_in && k < ldo) dst[(long)n * ldo + k] = (__bf16)tl[tx][ty + dy];
    }
}

// V slice of packed qkvb [1024,3072] -> vt [B,H,DK,S] bf16
__global__ void transpose_v(const __bf16* __restrict__ qkvb, __bf16* __restrict__ vt)
{
    __shared__ __bf16 tile[32][33];
    const int bh = blockIdx.z, b = bh >> 3, h = bh & 7;
    const int d0 = blockIdx.x * 32, i0 = blockIdx.y * 32;
    const int tx = threadIdx.x, ty = threadIdx.y;
    const __bf16* src = qkvb + 2 * ND + h * NDK;
#pragma unroll
    for (int dy = 0; dy < 32; dy += 8)
        tile[ty + dy][tx] = src[(long)(b * NS + i0 + ty + dy) * (3 * ND) + d0 + tx];
    __syncthreads();
#pragma unroll
    for (int dy = 0; dy < 32; dy += 8)
        vt[((long)bh * NDK + d0 + ty + dy) * NS + i0 + tx] = tile[tx][ty + dy];
}

// ---------------------------------------------------------------------------
// Fused softmax, loops over all 8 heads per (i,b) block: relation/mask rows
// loaded ONCE. scores bf16, rows LDSC=640 wide ([512,640) = qr table).
// ---------------------------------------------------------------------------
__global__ __launch_bounds__(256) void softmax_rel(
    const __bf16* __restrict__ scores,
    const int* __restrict__ relation, const int* __restrict__ mask,
    __bf16* __restrict__ attn, __bf16* __restrict__ attnR,
    float* __restrict__ loss_part, const int* __restrict__ sep_p)
{
    const int i = blockIdx.x, b = blockIdx.y;
    const int t = threadIdx.x;
    const int* rrow = relation + ((long)b * NS + i) * NS;
    const int* mrow = mask + ((long)b * NS + i) * NS;
    const int r0 = rrow[t], r1 = rrow[t + 256];
    const int m0 = mrow[t], m1 = mrow[t + 256];
    const int sep = *sep_p;
    const int lane = t & 63, wv = t >> 6;

    __shared__ float qrl[RPAD];
    __shared__ float bins[RPAD];
    __shared__ float red[4];

    const float sc = 0.088388347648318447f;  // 1/sqrt(128)
    float lsum = 0.f;

#pragma unroll 1
    for (int h = 0; h < NH; ++h) {
        const long bh = (long)(b * NH + h);
        const __bf16* srow = scores + (bh * NS + i) * LDSC;
        __bf16* arow = attn + (bh * NS + i) * NS;
        __bf16* aRrow = attnR + (bh * NS + i) * RPAD;

        if (t < RPAD) { qrl[t] = (float)srow[NS + t]; bins[t] = 0.f; }
        __syncthreads();

        float v0 = ((float)srow[t] + qrl[r0]) * sc;
        float v1 = ((float)srow[t + 256] + qrl[r1]) * sc;
        if (m0 == 0) v0 = -1e9f;
        if (m1 == 0) v1 = -1e9f;

        float mx = fmaxf(v0, v1);
#pragma unroll
        for (int o = 32; o > 0; o >>= 1) mx = fmaxf(mx, __shfl_xor(mx, o, 64));
        if (lane == 0) red[wv] = mx;
        __syncthreads();
        mx = fmaxf(fmaxf(red[0], red[1]), fmaxf(red[2], red[3]));
        __syncthreads();

        const float e0 = __expf(v0 - mx), e1 = __expf(v1 - mx);
        float sm = e0 + e1;
#pragma unroll
        for (int o = 32; o > 0; o >>= 1) sm += __shfl_xor(sm, o, 64);
        if (lane == 0) red[wv] = sm;
        __syncthreads();
        sm = red[0] + red[1] + red[2] + red[3];

        const float inv = 1.f / sm;
        const float a0 = e0 * inv, a1 = e1 * inv;
        arow[t] = (__bf16)a0;
        arow[t + 256] = (__bf16)a1;
        atomicAdd(&bins[r0], a0);
        atomicAdd(&bins[r1], a1);
        if (t < sep) lsum += a0;
        if (t + 256 < sep) lsum += a1;
        __syncthreads();  // fences bins atomics (and red reuse)
        if (t < RPAD) aRrow[t] = (__bf16)bins[t];
        __syncthreads();  // attnR read of bins before next head's reset
    }

#pragma unroll
    for (int o = 32; o > 0; o >>= 1) lsum += __shfl_xor(lsum, o, 64);
    if (lane == 0) red[wv] = lsum;
    __syncthreads();
    if (t == 0) loss_part[(long)b * NS + i] = red[0] + red[1] + red[2] + red[3];
}

// ctx split-K(2) reduce + fused attnR@rel_v + merge_heads -> ctxm bf16 [B*S, D]
__global__ __launch_bounds__(256) void ctx_reduce(
    const float* __restrict__ P, const __bf16* __restrict__ attnR,
    const __bf16* __restrict__ relvT, __bf16* __restrict__ ctxm)
{
    const int idx = blockIdx.x * 256 + threadIdx.x;
    const int d = idx & 127;
    const int i = (idx >> 7) & 511;
    const int h = (idx >> 16) & 7;
    const int b = idx >> 19;
    const long sP = (long)NBH * NS * NDK;
    float s = P[idx] + P[idx + sP];

    const bf16x8* ar = (const bf16x8*)(attnR + ((long)(idx >> 16) * NS + i) * RPAD);
    const bf16x8* rv = (const bf16x8*)(relvT + (long)d * RPAD);
    float acc = 0.f;
#pragma unroll
    for (int q = 0; q < 8; ++q) {
        bf16x8 a = ar[q], vv = rv[q];
#pragma unroll
        for (int j = 0; j < 8; ++j) acc += (float)a[j] * (float)vv[j];
    }
    ctxm[((long)(b * NS + i)) * ND + h * NDK + d] = (__bf16)(s + acc);
}

// Wo split-K(2) reduce + residual + bias, fused LN2 -> out fp32 + h2 bf16.
__global__ __launch_bounds__(256) void wo_reduce_ln(
    const float* __restrict__ P, const float* __restrict__ x,
    const float* __restrict__ bo, const float* __restrict__ g,
    const float* __restrict__ bb, float* __restrict__ out,
    __bf16* __restrict__ h2)
{
    const int row = blockIdx.x;
    const int t = threadIdx.x;
    const long i4 = (long)row * 256 + t;
    const long sP = (long)BSROWS * ND / 4;
    const float4* P4 = (const float4*)P;
    float4 s = P4[i4];
    const float4 t1 = P4[i4 + sP];
    s.x += t1.x; s.y += t1.y; s.z += t1.z; s.w += t1.w;
    const int col = t * 4;
    const float4 xv = ((const float4*)x)[i4];
    const float4 bv = *(const float4*)&bo[col];
    float4 o;
    o.x = s.x + xv.x + bv.x; o.y = s.y + xv.y + bv.y;
    o.z = s.z + xv.z + bv.z; o.w = s.w + xv.w + bv.w;
    ((float4*)out)[i4] = o;

    float sum = o.x + o.y + o.z + o.w;
    float sum2 = o.x * o.x + o.y * o.y + o.z * o.z + o.w * o.w;
#pragma unroll
    for (int of = 32; of > 0; of >>= 1) {
        sum += __shfl_xor(sum, of, 64);
        sum2 += __shfl_xor(sum2, of, 64);
    }
    __shared__ float red[8];
    const int lane = t & 63, wv = t >> 6;
    if (lane == 0) { red[wv] = sum; red[4 + wv] = sum2; }
    __syncthreads();
    sum = red[0] + red[1] + red[2] + red[3];
    sum2 = red[4] + red[5] + red[6] + red[7];
    const float mean = sum * (1.f / ND);
    const float var = sum2 * (1.f / ND) - mean * mean;
    const float rs = rsqrtf(var + 1e-5f);
    const float ov[4] = {o.x, o.y, o.z, o.w};
    bf16x4 hb;
#pragma unroll
    for (int j = 0; j < 4; ++j)
        hb[j] = (__bf16)((ov[j] - mean) * rs * g[col + j] + bb[col + j]);
    *(bf16x4*)&h2[(long)row * ND + col] = hb;
}

// FFN2 split-K(2) reduce: out += b2 + sum_2 partials. Block 0 also finalizes loss.
__global__ __launch_bounds__(256) void ffn2_reduce(
    const float* __restrict__ P, const float* __restrict__ b2, float* __restrict__ out,
    const float* __restrict__ loss_part, const float* __restrict__ hist,
    const int* __restrict__ sep_p, float* __restrict__ out_loss)
{
    const int i4 = blockIdx.x * 256 + threadIdx.x;
    const long sP = (long)BSROWS * ND / 4;
    const float4* P4 = (const float4*)P;
    float4 s = P4[i4];
    const float4 t1 = P4[i4 + sP];
    s.x += t1.x; s.y += t1.y; s.z += t1.z; s.w += t1.w;
    const int col = (i4 * 4) & (ND - 1);
    const float4 bv = *(const float4*)&b2[col];
    float4 o = ((float4*)out)[i4];
    o.x += s.x + bv.x; o.y += s.y + bv.y;
    o.z += s.z + bv.z; o.w += s.w + bv.w;
    ((float4*)out)[i4] = o;

    if (blockIdx.x == 0) {
        const int t = threadIdx.x;
        const float4 v = ((const float4*)loss_part)[t];   // 1024 floats total
        float ls = v.x + v.y + v.z + v.w;
#pragma unroll
        for (int of = 32; of > 0; of >>= 1) ls += __shfl_xor(ls, of, 64);
        __shared__ float red[4];
        if ((t & 63) == 0) red[t >> 6] = ls;
        __syncthreads();
        if (t == 0) {
            const int sep = *sep_p;
            const float total = red[0] + red[1] + red[2] + red[3];
            const float denom = (float)NB * NH * NS * (float)(sep > 0 ? sep : 1);
            out_loss[0] = (sep > 0) ? hist[0] * total / denom : 0.f;
        }
    }
}

// ---------------------------------------------------------------------------
static inline int cdiv(int a, int b) { return (a + b - 1) / b; }

extern "C" void kernel_launch(void* const* d_in, const int* in_sizes, int n_in,
                              void* d_out, int out_size, void* d_ws, size_t ws_size,
                              hipStream_t stream)
{
    const float* x      = (const float*)d_in[0];
    const int* relation = (const int*)d_in[1];
    const int* mask     = (const int*)d_in[2];
    const int* sep_p    = (const int*)d_in[3];
    const float* hist   = (const float*)d_in[4];
    const float* Wq = (const float*)d_in[5],  *bq = (const float*)d_in[6];
    const float* Wk = (const float*)d_in[7],  *bk = (const float*)d_in[8];
    const float* Wv = (const float*)d_in[9],  *bv = (const float*)d_in[10];
    const float* Wo = (const float*)d_in[11], *bo = (const float*)d_in[12];
    const float* relk = (const float*)d_in[13];
    const float* relv = (const float*)d_in[14];
    const float* ln1g = (const float*)d_in[15], *ln1b = (const float*)d_in[16];
    const float* ln2g = (const float*)d_in[17], *ln2b = (const float*)d_in[18];
    const float* W1 = (const float*)d_in[19], *b1 = (const float*)d_in[20];
    const float* W2 = (const float*)d_in[21], *b2 = (const float*)d_in[22];
    const int R = in_sizes[13] / NDK;  // 51

    float* out = (float*)d_out;
    float* out_loss = out + (long)BSROWS * ND;

    char* p = (char*)d_ws;
    auto alloc = [&](size_t bytes) -> void* {
        void* r = (void*)p;
        p += (bytes + 255) & ~(size_t)255;
        return r;
    };
    __bf16* WqkvT   = (__bf16*)alloc((size_t)3 * ND * ND * 2);
    __bf16* WoT     = (__bf16*)alloc((size_t)ND * ND * 2);
    __bf16* W1T     = (__bf16*)alloc((size_t)NDFF * ND * 2);
    __bf16* W2T     = (__bf16*)alloc((size_t)ND * NDFF * 2);
    __bf16* relkT   = (__bf16*)alloc((size_t)128 * NDK * 2);
    __bf16* relvT   = (__bf16*)alloc((size_t)NDK * RPAD * 2);
    float*  biasqkv = (float*)alloc((size_t)3 * ND * 4);
    __bf16* h1      = (__bf16*)alloc((size_t)BSROWS * ND * 2);
    __bf16* qkvb    = (__bf16*)alloc((size_t)BSROWS * 3 * ND * 2);
    __bf16* vt      = (__bf16*)alloc((size_t)NBH * NDK * NS * 2);
    __bf16* attnb   = (__bf16*)alloc((size_t)NBH * NS * NS * 2);
    __bf16* attnR   = (__bf16*)alloc((size_t)NBH * NS * RPAD * 2);
    __bf16* ctxm    = (__bf16*)alloc((size_t)BSROWS * ND * 2);
    __bf16* h2      = (__bf16*)alloc((size_t)BSROWS * ND * 2);
    __bf16* F1      = (__bf16*)alloc((size_t)BSROWS * NDFF * 2);
    float*  loss_part = (float*)alloc((size_t)NB * NS * 4);
    float*  arena   = (float*)alloc((size_t)64 * 1024 * 1024);
    // arena aliasing (lifetimes disjoint), byte offsets:
    __bf16* scoresb = (__bf16*)arena;                   // 10.5MB, dead after softmax
    float* ctxPart  = arena + (size_t)3 * 1024 * 1024;  // [12,20)MB
    float* woPart   = arena;                            // [0,8)MB
    float* f2Part   = arena + (size_t)2 * 1024 * 1024;  // [8,16)MB

    const dim3 tb(32, 8);
    prep_weights<<<12372, tb, 0, stream>>>(Wq, Wk, Wv, Wo, W1, W2, relv,
                                           bq, bk, bv, relk,
                                           WqkvT, WoT, W1T, W2T, relvT,
                                           biasqkv, relkT, R);

    ln_bf16<<<BSROWS, 256, 0, stream>>>(x, ln1g, ln1b, h1);

    // QKV: [1024,1024] @ [3072,1024]^T -> qkvb bf16 (768 blocks, nt=16)
    gemm64<<<dim3(48, 16, 1), 256, 0, stream>>>(
        h1, WqkvT, nullptr, nullptr, qkvb, biasqkv,
        ND, ND, ND, 3 * ND,
        0, 0, 1, 0, 0, 1, 0, 1, 0, 0);

    transpose_v<<<dim3(4, 16, NBH), tb, 0, stream>>>(qkvb, vt);

    // scores+qr fused: per-head q @ [k^T | relk^T] -> scoresb bf16 [512,640]
    gemm64<<<dim3(10, 8, NBH), 256, 0, stream>>>(
        qkvb, qkvb + ND, relkT, nullptr, scoresb, nullptr,
        NDK, 3 * ND, 3 * ND, LDSC,
        (long)NS * 3 * ND, NDK, NH,
        (long)NS * 3 * ND, NDK, NH,
        (long)NS * LDSC, 1, 0, 4);

    softmax_rel<<<dim3(NS, NB), 256, 0, stream>>>(
        scoresb, relation, mask, attnb, attnR, loss_part, sep_p);

    // ctx = attn @ v : split-K x2 (Ksp=256, nt=4), 512 blocks
    gemm64<<<dim3(2, 8, NBH * 2), 256, 0, stream>>>(
        attnb, vt, nullptr, ctxPart, nullptr, nullptr,
        256, NS, NS, NDK,
        (long)NS * NS, 0, 1,
        (long)NDK * NS, 0, 1,
        (long)NS * NDK, 2, (long)NBH * NS * NDK, 0);

    ctx_reduce<<<4096, 256, 0, stream>>>(ctxPart, attnR, relvT, ctxm);

    // attn_out partials: ctxm @ Wo, split-K x2 (Ksp=512, nt=8), 512 blocks
    gemm64<<<dim3(16, 16, 2), 256, 0, stream>>>(
        ctxm, WoT, nullptr, woPart, nullptr, nullptr,
        512, ND, ND, ND,
        0, 0, 1, 0, 0, 1,
        0, 2, (long)BSROWS * ND, 0);

    // fused: out = x + bo + sum_2 partials; h2 = LN2(out)
    wo_reduce_ln<<<BSROWS, 256, 0, stream>>>(woPart, x, bo, ln2g, ln2b, out, h2);

    // FFN1: relu(h2 @ W1 + b1) -> F1 bf16 (1024 blocks, nt=16)
    gemm64<<<dim3(64, 16, 1), 256, 0, stream>>>(
        h2, W1T, nullptr, nullptr, F1, b1,
        ND, ND, ND, NDFF,
        0, 0, 1, 0, 0, 1, 0, 1, 0, 1);

    // FFN2 partials: F1 @ W2, split-K x2 (Ksp=2048, nt=32), 512 blocks
    gemm64<<<dim3(16, 16, 2), 256, 0, stream>>>(
        F1, W2T, nullptr, f2Part, nullptr, nullptr,
        2048, NDFF, NDFF, ND,
        0, 0, 1, 0, 0, 1,
        0, 2, (long)BSROWS * ND, 0);

    // FFN2 reduce + fused loss finalize
    ffn2_reduce<<<1024, 256, 0, stream>>>(f2Part, b2, out,
                                          loss_part, hist, sep_p, out_loss);
}

// Round 9
// 162.217 us; speedup vs baseline: 1.3823x; 1.0031x over previous
//
#include <hip/hip_runtime.h>
#include <hip/hip_bf16.h>

#define NB 2
#define NS 512
#define ND 1024
#define NH 8
#define NDK 128
#define NDFF 4096
#define RPAD 64
#define LDSC 640              /* scores row stride: 512 scores + 128 qr */
#define BSROWS 1024           /* B*S */
#define NBH 16                /* B*H */

typedef __bf16 bf16x8 __attribute__((ext_vector_type(8)));
typedef __bf16 bf16x4 __attribute__((ext_vector_type(4)));
typedef float f32x4 __attribute__((ext_vector_type(4)));

#define BM 64
#define BN 64
#define BK 64

__device__ __forceinline__ void gload16(const void* g, void* l) {
    __builtin_amdgcn_global_load_lds(
        (const __attribute__((address_space(1))) void*)g,
        (__attribute__((address_space(3))) void*)l, 16, 0, 0);
}

// ---------------------------------------------------------------------------
// Counted-vmcnt pipelined MFMA GEMM, 64x64 tile, BK=64, 4 waves (each 32x32).
// 2 LDS buffers; loads stay in flight across barriers (vmcnt(4)).
// Both-sides XOR swizzle on LDS; T5 setprio around MFMA cluster; T1
// XCD-bijective workgroup remap (grid size must be; all callers are % 8 == 0
// or the m204 formula handles the remainder). Requires nt = Ksp/BK even >= 2.
// flags: 1=relu, 4=fused-rel-B (col tiles >= NS read Brel [128,128]).
// ---------------------------------------------------------------------------
__global__ __launch_bounds__(256, 4) void gemm64(
    const __bf16* __restrict__ A, const __bf16* __restrict__ Bt,
    const __bf16* __restrict__ Brel,
    float* __restrict__ Cf, __bf16* __restrict__ Cb,
    const float* __restrict__ bias,
    int Ksp, int lda, int ldb, int ldc,
    long sA, long sA2, int zdivA,
    long sB, long sB2, int zdivB,
    long sC, int nsplit, long sPart, int flags)
{
    __shared__ __bf16 As0[BM * BK];
    __shared__ __bf16 As1[BM * BK];
    __shared__ __bf16 Bs0[BN * BK];
    __shared__ __bf16 Bs1[BN * BK];

    // T1: XCD-bijective remap of the linear workgroup id (m204 formula).
    const unsigned gx = gridDim.x, gy = gridDim.y;
    const unsigned n = gx * gy * gridDim.z;
    const unsigned o = blockIdx.x + gx * (blockIdx.y + gy * blockIdx.z);
    const unsigned q = n >> 3, r = n & 7, xcd = o & 7;
    const unsigned nl = (xcd < r ? xcd * (q + 1) : r * (q + 1) + (xcd - r) * q) + (o >> 3);
    const unsigned bx = nl % gx, tmp = nl / gx;
    const unsigned by = tmp % gy, bz = tmp / gy;

    const int z = bz;
    const int bh = z / nsplit, sp = z - bh * nsplit;
    const long kbase = (long)sp * Ksp;
    A  += (long)(bh / zdivA) * sA + (long)(bh % zdivA) * sA2 + kbase;
    Bt += (long)(bh / zdivB) * sB + (long)(bh % zdivB) * sB2 + kbase;
    const long cbase = (long)bh * sC + (long)sp * sPart;

    const int tM = by * BM, tN = bx * BN;
    const int t = threadIdx.x, lane = t & 63, w = t >> 6;
    const int wr = w >> 1, wc = w & 1;

    const __bf16* Bbase = Bt;
    int ldbx = ldb, tNB = tN;
    if ((flags & 4) && tN >= NS) { Bbase = Brel + kbase; ldbx = 128; tNB = tN - NS; }

    const int srow = lane >> 3;
    const int scolE = ((((lane & 7) << 4) ^ (srow << 4)) >> 1);

    const __bf16* gA = A + (long)(tM + srow) * lda + scolE;
    const __bf16* gB = Bbase + (long)(tNB + srow) * ldbx + scolE;

    f32x4 acc[2][2];
#pragma unroll
    for (int m = 0; m < 2; ++m)
#pragma unroll
        for (int nn = 0; nn < 2; ++nn)
#pragma unroll
            for (int j = 0; j < 4; ++j) acc[m][nn][j] = 0.f;

    const int r16 = lane & 15;
    const int kq = (lane >> 4) * 8;
    const int xorE = (r16 & 7) * 8;
    const int nt = Ksp / BK;

    auto STAGE = [&](__bf16* as, __bf16* bs, int k0) {
#pragma unroll
        for (int i = 0; i < 2; ++i) {
            const int rr = (w + i * 4) * 8;
            gload16(gA + (long)rr * lda + k0, (void*)&as[rr * BK]);
            gload16(gB + (long)rr * ldbx + k0, (void*)&bs[rr * BK]);
        }
    };
    auto COMPUTE = [&](const __bf16* as, const __bf16* bs) {
        __builtin_amdgcn_s_setprio(1);      // T5: favor MFMA-entering wave
#pragma unroll
        for (int ks = 0; ks < 2; ++ks) {
            bf16x8 af[2], bv[2];
#pragma unroll
            for (int m = 0; m < 2; ++m)
                af[m] = *(const bf16x8*)&as[(wr * 32 + m * 16 + r16) * BK + ((ks * 32 + kq) ^ xorE)];
#pragma unroll
            for (int nn = 0; nn < 2; ++nn)
                bv[nn] = *(const bf16x8*)&bs[(wc * 32 + nn * 16 + r16) * BK + ((ks * 32 + kq) ^ xorE)];
#pragma unroll
            for (int m = 0; m < 2; ++m)
#pragma unroll
                for (int nn = 0; nn < 2; ++nn)
                    acc[m][nn] = __builtin_amdgcn_mfma_f32_16x16x32_bf16(af[m], bv[nn], acc[m][nn], 0, 0, 0);
        }
        __builtin_amdgcn_s_setprio(0);
    };

    STAGE(As0, Bs0, 0);
    STAGE(As1, Bs1, BK);
    for (int tt = 0; tt < nt; tt += 2) {
        asm volatile("s_waitcnt vmcnt(4)\n\ts_barrier" ::: "memory");
        COMPUTE(As0, Bs0);
        asm volatile("s_waitcnt lgkmcnt(0)\n\ts_barrier" ::: "memory");
        const bool more = (tt + 2 < nt);
        if (more) {
            STAGE(As0, Bs0, (tt + 2) * BK);
            asm volatile("s_waitcnt vmcnt(4)\n\ts_barrier" ::: "memory");
        } else {
            asm volatile("s_waitcnt vmcnt(0)\n\ts_barrier" ::: "memory");
        }
        COMPUTE(As1, Bs1);
        asm volatile("s_waitcnt lgkmcnt(0)\n\ts_barrier" ::: "memory");
        if (more) STAGE(As1, Bs1, (tt + 3) * BK);
    }

    const bool relu = (flags & 1) != 0;
#pragma unroll
    for (int m = 0; m < 2; ++m) {
        const int gr0 = tM + wr * 32 + m * 16 + (lane >> 4) * 4;
#pragma unroll
        for (int nn = 0; nn < 2; ++nn) {
            const int gc = tN + wc * 32 + nn * 16 + (lane & 15);
            const float bb = bias ? bias[gc] : 0.f;
#pragma unroll
            for (int j = 0; j < 4; ++j) {
                float v = acc[m][nn][j] + bb;
                if (relu) v = fmaxf(v, 0.f);
                const long idx = cbase + (long)(gr0 + j) * ldc + gc;
                if (Cb) Cb[idx] = (__bf16)v;
                else Cf[idx] = v;
            }
        }
    }
}

// ---------------------------------------------------------------------------
// Fused prep: all fp32->bf16 weight transposes + bias pack + relk pad + LN1.
// grid.x = 13396 blocks of (32,8):
//   [0,12288)      : weight transposes (32x32 tiles)
//   [12288,12296)  : relv transpose
//   [12296,12372)  : bias pack + relk pad (flat)
//   [12372,13396)  : LN1 rows (one block per row of x)
// ---------------------------------------------------------------------------
__global__ void prep_weights(
    const float* __restrict__ Wq, const float* __restrict__ Wk,
    const float* __restrict__ Wv, const float* __restrict__ Wo,
    const float* __restrict__ W1, const float* __restrict__ W2,
    const float* __restrict__ relv,
    const float* __restrict__ bq, const float* __restrict__ bk,
    const float* __restrict__ bv, const float* __restrict__ relk,
    const float* __restrict__ x, const float* __restrict__ ln1g,
    const float* __restrict__ ln1b,
    __bf16* __restrict__ WqkvT, __bf16* __restrict__ WoT,
    __bf16* __restrict__ W1T, __bf16* __restrict__ W2T,
    __bf16* __restrict__ relvT, float* __restrict__ biasqkv,
    __bf16* __restrict__ relkT, __bf16* __restrict__ h1, int R)
{
    const int tile = blockIdx.x;
    const int t = threadIdx.y * 32 + threadIdx.x;

    if (tile >= 12372) {   // LN1 row
        const long row = tile - 12372;
        const float* xr = x + row * ND;
        float4 v = reinterpret_cast<const float4*>(xr)[t];
        float s = v.x + v.y + v.z + v.w;
        float s2 = v.x * v.x + v.y * v.y + v.z * v.z + v.w * v.w;
#pragma unroll
        for (int o = 32; o > 0; o >>= 1) {
            s += __shfl_xor(s, o, 64);
            s2 += __shfl_xor(s2, o, 64);
        }
        __shared__ float red[8];
        const int lane = t & 63, wv = t >> 6;
        if (lane == 0) { red[wv] = s; red[4 + wv] = s2; }
        __syncthreads();
        s = red[0] + red[1] + red[2] + red[3];
        s2 = red[4] + red[5] + red[6] + red[7];
        const float mean = s * (1.f / ND);
        const float var = s2 * (1.f / ND) - mean * mean;
        const float rs = rsqrtf(var + 1e-5f);
        const float xv[4] = {v.x, v.y, v.z, v.w};
        bf16x4 o;
#pragma unroll
        for (int j = 0; j < 4; ++j) {
            const int c = t * 4 + j;
            o[j] = (__bf16)((xv[j] - mean) * rs * ln1g[c] + ln1b[c]);
        }
        *(bf16x4*)&h1[row * ND + t * 4] = o;
        return;
    }
    if (tile >= 12296) {   // bias pack + relk pad (flat)
        const int ft = (tile - 12296) * 256 + t;
        if (ft < ND) biasqkv[ft] = bq[ft];
        else if (ft < 2 * ND) biasqkv[ft] = bk[ft - ND];
        else if (ft < 3 * ND) biasqkv[ft] = bv[ft - 2 * ND];
        else {
            const int idx = ft - 3 * ND;
            if (idx < 128 * NDK) {
                const int r = idx / NDK;
                relkT[idx] = (r < R) ? (__bf16)relk[idx] : (__bf16)0.f;
            }
        }
        return;
    }
    const float* src; __bf16* dst;
    int rows_in, cols_in, ldo, kx, ny;
    if (tile < 4096) {
        const int m = tile >> 10, r = tile & 1023;
        kx = r & 31; ny = r >> 5;
        rows_in = 1024; cols_in = 1024; ldo = 1024;
        src = m == 0 ? Wq : m == 1 ? Wk : m == 2 ? Wv : Wo;
        dst = m == 3 ? WoT : WqkvT + (size_t)m * 1024 * 1024;
    } else if (tile < 8192) {
        const int r = tile - 4096;
        kx = r & 31; ny = r >> 5;
        rows_in = 1024; cols_in = 4096; ldo = 1024; src = W1; dst = W1T;
    } else if (tile < 12288) {
        const int r = tile - 8192;
        kx = r & 127; ny = r >> 7;
        rows_in = 4096; cols_in = 1024; ldo = 4096; src = W2; dst = W2T;
    } else {
        const int r = tile - 12288;
        kx = r & 1; ny = r >> 1;
        rows_in = R; cols_in = 128; ldo = 64; src = relv; dst = relvT;
    }

    __shared__ float tl[32][33];
    const int k0 = kx * 32, n0 = ny * 32;
    const int tx = threadIdx.x, ty = threadIdx.y;
#pragma unroll
    for (int dy = 0; dy < 32; dy += 8) {
        const int k = k0 + ty + dy, nn = n0 + tx;
        tl[ty + dy][tx] = (k < rows_in && nn < cols_in) ? src[(long)k * cols_in + nn] : 0.f;
    }
    __syncthreads();
#pragma unroll
    for (int dy = 0; dy < 32; dy += 8) {
        const int nn = n0 + ty + dy, k = k0 + tx;
        if (nn < cols_in && k < ldo) dst[(long)nn * ldo + k] = (__bf16)tl[tx][ty + dy];
    }
}

// V slice of packed qkvb [1024,3072] -> vt [B,H,DK,S] bf16
__global__ void transpose_v(const __bf16* __restrict__ qkvb, __bf16* __restrict__ vt)
{
    __shared__ __bf16 tile[32][33];
    const int bh = blockIdx.z, b = bh >> 3, h = bh & 7;
    const int d0 = blockIdx.x * 32, i0 = blockIdx.y * 32;
    const int tx = threadIdx.x, ty = threadIdx.y;
    const __bf16* src = qkvb + 2 * ND + h * NDK;
#pragma unroll
    for (int dy = 0; dy < 32; dy += 8)
        tile[ty + dy][tx] = src[(long)(b * NS + i0 + ty + dy) * (3 * ND) + d0 + tx];
    __syncthreads();
#pragma unroll
    for (int dy = 0; dy < 32; dy += 8)
        vt[((long)bh * NDK + d0 + ty + dy) * NS + i0 + tx] = tile[tx][ty + dy];
}

// ---------------------------------------------------------------------------
// Fused softmax, loops over all 8 heads per (i,b) block: relation/mask rows
// loaded ONCE. scores bf16, rows LDSC=640 wide ([512,640) = qr table).
// ---------------------------------------------------------------------------
__global__ __launch_bounds__(256) void softmax_rel(
    const __bf16* __restrict__ scores,
    const int* __restrict__ relation, const int* __restrict__ mask,
    __bf16* __restrict__ attn, __bf16* __restrict__ attnR,
    float* __restrict__ loss_part, const int* __restrict__ sep_p)
{
    const int i = blockIdx.x, b = blockIdx.y;
    const int t = threadIdx.x;
    const int* rrow = relation + ((long)b * NS + i) * NS;
    const int* mrow = mask + ((long)b * NS + i) * NS;
    const int r0 = rrow[t], r1 = rrow[t + 256];
    const int m0 = mrow[t], m1 = mrow[t + 256];
    const int sep = *sep_p;
    const int lane = t & 63, wv = t >> 6;

    __shared__ float qrl[RPAD];
    __shared__ float bins[RPAD];
    __shared__ float red[4];

    const float sc = 0.088388347648318447f;  // 1/sqrt(128)
    float lsum = 0.f;

#pragma unroll 1
    for (int h = 0; h < NH; ++h) {
        const long bh = (long)(b * NH + h);
        const __bf16* srow = scores + (bh * NS + i) * LDSC;
        __bf16* arow = attn + (bh * NS + i) * NS;
        __bf16* aRrow = attnR + (bh * NS + i) * RPAD;

        if (t < RPAD) { qrl[t] = (float)srow[NS + t]; bins[t] = 0.f; }
        __syncthreads();

        float v0 = ((float)srow[t] + qrl[r0]) * sc;
        float v1 = ((float)srow[t + 256] + qrl[r1]) * sc;
        if (m0 == 0) v0 = -1e9f;
        if (m1 == 0) v1 = -1e9f;

        float mx = fmaxf(v0, v1);
#pragma unroll
        for (int o = 32; o > 0; o >>= 1) mx = fmaxf(mx, __shfl_xor(mx, o, 64));
        if (lane == 0) red[wv] = mx;
        __syncthreads();
        mx = fmaxf(fmaxf(red[0], red[1]), fmaxf(red[2], red[3]));
        __syncthreads();

        const float e0 = __expf(v0 - mx), e1 = __expf(v1 - mx);
        float sm = e0 + e1;
#pragma unroll
        for (int o = 32; o > 0; o >>= 1) sm += __shfl_xor(sm, o, 64);
        if (lane == 0) red[wv] = sm;
        __syncthreads();
        sm = red[0] + red[1] + red[2] + red[3];

        const float inv = 1.f / sm;
        const float a0 = e0 * inv, a1 = e1 * inv;
        arow[t] = (__bf16)a0;
        arow[t + 256] = (__bf16)a1;
        atomicAdd(&bins[r0], a0);
        atomicAdd(&bins[r1], a1);
        if (t < sep) lsum += a0;
        if (t + 256 < sep) lsum += a1;
        __syncthreads();  // fences bins atomics (and red reuse)
        if (t < RPAD) aRrow[t] = (__bf16)bins[t];
        __syncthreads();  // attnR read of bins before next head's reset
    }

#pragma unroll
    for (int o = 32; o > 0; o >>= 1) lsum += __shfl_xor(lsum, o, 64);
    if (lane == 0) red[wv] = lsum;
    __syncthreads();
    if (t == 0) loss_part[(long)b * NS + i] = red[0] + red[1] + red[2] + red[3];
}

// ctx split-K(2) reduce + fused attnR@rel_v + merge_heads -> ctxm bf16 [B*S, D]
__global__ __launch_bounds__(256) void ctx_reduce(
    const float* __restrict__ P, const __bf16* __restrict__ attnR,
    const __bf16* __restrict__ relvT, __bf16* __restrict__ ctxm)
{
    const int idx = blockIdx.x * 256 + threadIdx.x;
    const int d = idx & 127;
    const int i = (idx >> 7) & 511;
    const int h = (idx >> 16) & 7;
    const int b = idx >> 19;
    const long sP = (long)NBH * NS * NDK;
    float s = P[idx] + P[idx + sP];

    const bf16x8* ar = (const bf16x8*)(attnR + ((long)(idx >> 16) * NS + i) * RPAD);
    const bf16x8* rv = (const bf16x8*)(relvT + (long)d * RPAD);
    float acc = 0.f;
#pragma unroll
    for (int q = 0; q < 8; ++q) {
        bf16x8 a = ar[q], vv = rv[q];
#pragma unroll
        for (int j = 0; j < 8; ++j) acc += (float)a[j] * (float)vv[j];
    }
    ctxm[((long)(b * NS + i)) * ND + h * NDK + d] = (__bf16)(s + acc);
}

// Wo split-K(2) reduce + residual + bias, fused LN2 -> out fp32 + h2 bf16.
__global__ __launch_bounds__(256) void wo_reduce_ln(
    const float* __restrict__ P, const float* __restrict__ x,
    const float* __restrict__ bo, const float* __restrict__ g,
    const float* __restrict__ bb, float* __restrict__ out,
    __bf16* __restrict__ h2)
{
    const int row = blockIdx.x;
    const int t = threadIdx.x;
    const long i4 = (long)row * 256 + t;
    const long sP = (long)BSROWS * ND / 4;
    const float4* P4 = (const float4*)P;
    float4 s = P4[i4];
    const float4 t1 = P4[i4 + sP];
    s.x += t1.x; s.y += t1.y; s.z += t1.z; s.w += t1.w;
    const int col = t * 4;
    const float4 xv = ((const float4*)x)[i4];
    const float4 bv = *(const float4*)&bo[col];
    float4 o;
    o.x = s.x + xv.x + bv.x; o.y = s.y + xv.y + bv.y;
    o.z = s.z + xv.z + bv.z; o.w = s.w + xv.w + bv.w;
    ((float4*)out)[i4] = o;

    float sum = o.x + o.y + o.z + o.w;
    float sum2 = o.x * o.x + o.y * o.y + o.z * o.z + o.w * o.w;
#pragma unroll
    for (int of = 32; of > 0; of >>= 1) {
        sum += __shfl_xor(sum, of, 64);
        sum2 += __shfl_xor(sum2, of, 64);
    }
    __shared__ float red[8];
    const int lane = t & 63, wv = t >> 6;
    if (lane == 0) { red[wv] = sum; red[4 + wv] = sum2; }
    __syncthreads();
    sum = red[0] + red[1] + red[2] + red[3];
    sum2 = red[4] + red[5] + red[6] + red[7];
    const float mean = sum * (1.f / ND);
    const float var = sum2 * (1.f / ND) - mean * mean;
    const float rs = rsqrtf(var + 1e-5f);
    const float ov[4] = {o.x, o.y, o.z, o.w};
    bf16x4 hb;
#pragma unroll
    for (int j = 0; j < 4; ++j)
        hb[j] = (__bf16)((ov[j] - mean) * rs * g[col + j] + bb[col + j]);
    *(bf16x4*)&h2[(long)row * ND + col] = hb;
}

// FFN2 split-K(2) reduce: out += b2 + sum_2 partials. Block 0 also finalizes loss.
__global__ __launch_bounds__(256) void ffn2_reduce(
    const float* __restrict__ P, const float* __restrict__ b2, float* __restrict__ out,
    const float* __restrict__ loss_part, const float* __restrict__ hist,
    const int* __restrict__ sep_p, float* __restrict__ out_loss)
{
    const int i4 = blockIdx.x * 256 + threadIdx.x;
    const long sP = (long)BSROWS * ND / 4;
    const float4* P4 = (const float4*)P;
    float4 s = P4[i4];
    const float4 t1 = P4[i4 + sP];
    s.x += t1.x; s.y += t1.y; s.z += t1.z; s.w += t1.w;
    const int col = (i4 * 4) & (ND - 1);
    const float4 bv = *(const float4*)&b2[col];
    float4 o = ((float4*)out)[i4];
    o.x += s.x + bv.x; o.y += s.y + bv.y;
    o.z += s.z + bv.z; o.w += s.w + bv.w;
    ((float4*)out)[i4] = o;

    if (blockIdx.x == 0) {
        const int t = threadIdx.x;
        const float4 v = ((const float4*)loss_part)[t];   // 1024 floats total
        float ls = v.x + v.y + v.z + v.w;
#pragma unroll
        for (int of = 32; of > 0; of >>= 1) ls += __shfl_xor(ls, of, 64);
        __shared__ float red[4];
        if ((t & 63) == 0) red[t >> 6] = ls;
        __syncthreads();
        if (t == 0) {
            const int sep = *sep_p;
            const float total = red[0] + red[1] + red[2] + red[3];
            const float denom = (float)NB * NH * NS * (float)(sep > 0 ? sep : 1);
            out_loss[0] = (sep > 0) ? hist[0] * total / denom : 0.f;
        }
    }
}

// ---------------------------------------------------------------------------
static inline int cdiv(int a, int b) { return (a + b - 1) / b; }

extern "C" void kernel_launch(void* const* d_in, const int* in_sizes, int n_in,
                              void* d_out, int out_size, void* d_ws, size_t ws_size,
                              hipStream_t stream)
{
    const float* x      = (const float*)d_in[0];
    const int* relation = (const int*)d_in[1];
    const int* mask     = (const int*)d_in[2];
    const int* sep_p    = (const int*)d_in[3];
    const float* hist   = (const float*)d_in[4];
    const float* Wq = (const float*)d_in[5],  *bq = (const float*)d_in[6];
    const float* Wk = (const float*)d_in[7],  *bk = (const float*)d_in[8];
    const float* Wv = (const float*)d_in[9],  *bv = (const float*)d_in[10];
    const float* Wo = (const float*)d_in[11], *bo = (const float*)d_in[12];
    const float* relk = (const float*)d_in[13];
    const float* relv = (const float*)d_in[14];
    const float* ln1g = (const float*)d_in[15], *ln1b = (const float*)d_in[16];
    const float* ln2g = (const float*)d_in[17], *ln2b = (const float*)d_in[18];
    const float* W1 = (const float*)d_in[19], *b1 = (const float*)d_in[20];
    const float* W2 = (const float*)d_in[21], *b2 = (const float*)d_in[22];
    const int R = in_sizes[13] / NDK;  // 51

    float* out = (float*)d_out;
    float* out_loss = out + (long)BSROWS * ND;

    char* p = (char*)d_ws;
    auto alloc = [&](size_t bytes) -> void* {
        void* r = (void*)p;
        p += (bytes + 255) & ~(size_t)255;
        return r;
    };
    __bf16* WqkvT   = (__bf16*)alloc((size_t)3 * ND * ND * 2);
    __bf16* WoT     = (__bf16*)alloc((size_t)ND * ND * 2);
    __bf16* W1T     = (__bf16*)alloc((size_t)NDFF * ND * 2);
    __bf16* W2T     = (__bf16*)alloc((size_t)ND * NDFF * 2);
    __bf16* relkT   = (__bf16*)alloc((size_t)128 * NDK * 2);
    __bf16* relvT   = (__bf16*)alloc((size_t)NDK * RPAD * 2);
    float*  biasqkv = (float*)alloc((size_t)3 * ND * 4);
    __bf16* h1      = (__bf16*)alloc((size_t)BSROWS * ND * 2);
    __bf16* qkvb    = (__bf16*)alloc((size_t)BSROWS * 3 * ND * 2);
    __bf16* vt      = (__bf16*)alloc((size_t)NBH * NDK * NS * 2);
    __bf16* attnb   = (__bf16*)alloc((size_t)NBH * NS * NS * 2);
    __bf16* attnR   = (__bf16*)alloc((size_t)NBH * NS * RPAD * 2);
    __bf16* ctxm    = (__bf16*)alloc((size_t)BSROWS * ND * 2);
    __bf16* h2      = (__bf16*)alloc((size_t)BSROWS * ND * 2);
    __bf16* F1      = (__bf16*)alloc((size_t)BSROWS * NDFF * 2);
    float*  loss_part = (float*)alloc((size_t)NB * NS * 4);
    float*  arena   = (float*)alloc((size_t)64 * 1024 * 1024);
    // arena aliasing (lifetimes disjoint):
    __bf16* scoresb = (__bf16*)arena;                   // 10.5MB, dead after softmax
    float* ctxPart  = arena + (size_t)3 * 1024 * 1024;  // [12,20)MB
    float* woPart   = arena;                            // [0,8)MB
    float* f2Part   = arena + (size_t)2 * 1024 * 1024;  // [8,16)MB

    const dim3 tb(32, 8);
    // fused weight prep + LN1 (13396 blocks)
    prep_weights<<<13396, tb, 0, stream>>>(Wq, Wk, Wv, Wo, W1, W2, relv,
                                           bq, bk, bv, relk, x, ln1g, ln1b,
                                           WqkvT, WoT, W1T, W2T, relvT,
                                           biasqkv, relkT, h1, R);

    // QKV: [1024,1024] @ [3072,1024]^T -> qkvb bf16 (768 blocks, nt=16)
    gemm64<<<dim3(48, 16, 1), 256, 0, stream>>>(
        h1, WqkvT, nullptr, nullptr, qkvb, biasqkv,
        ND, ND, ND, 3 * ND,
        0, 0, 1, 0, 0, 1, 0, 1, 0, 0);

    transpose_v<<<dim3(4, 16, NBH), tb, 0, stream>>>(qkvb, vt);

    // scores+qr fused: per-head q @ [k^T | relk^T] -> scoresb bf16 [512,640]
    gemm64<<<dim3(10, 8, NBH), 256, 0, stream>>>(
        qkvb, qkvb + ND, relkT, nullptr, scoresb, nullptr,
        NDK, 3 * ND, 3 * ND, LDSC,
        (long)NS * 3 * ND, NDK, NH,
        (long)NS * 3 * ND, NDK, NH,
        (long)NS * LDSC, 1, 0, 4);

    softmax_rel<<<dim3(NS, NB), 256, 0, stream>>>(
        scoresb, relation, mask, attnb, attnR, loss_part, sep_p);

    // ctx = attn @ v : split-K x2 (Ksp=256, nt=4), 512 blocks
    gemm64<<<dim3(2, 8, NBH * 2), 256, 0, stream>>>(
        attnb, vt, nullptr, ctxPart, nullptr, nullptr,
        256, NS, NS, NDK,
        (long)NS * NS, 0, 1,
        (long)NDK * NS, 0, 1,
        (long)NS * NDK, 2, (long)NBH * NS * NDK, 0);

    ctx_reduce<<<4096, 256, 0, stream>>>(ctxPart, attnR, relvT, ctxm);

    // attn_out partials: ctxm @ Wo, split-K x2 (Ksp=512, nt=8), 512 blocks
    gemm64<<<dim3(16, 16, 2), 256, 0, stream>>>(
        ctxm, WoT, nullptr, woPart, nullptr, nullptr,
        512, ND, ND, ND,
        0, 0, 1, 0, 0, 1,
        0, 2, (long)BSROWS * ND, 0);

    // fused: out = x + bo + sum_2 partials; h2 = LN2(out)
    wo_reduce_ln<<<BSROWS, 256, 0, stream>>>(woPart, x, bo, ln2g, ln2b, out, h2);

    // FFN1: relu(h2 @ W1 + b1) -> F1 bf16 (1024 blocks, nt=16)
    gemm64<<<dim3(64, 16, 1), 256, 0, stream>>>(
        h2, W1T, nullptr, nullptr, F1, b1,
        ND, ND, ND, NDFF,
        0, 0, 1, 0, 0, 1, 0, 1, 0, 1);

    // FFN2 partials: F1 @ W2, split-K x2 (Ksp=2048, nt=32), 512 blocks
    gemm64<<<dim3(16, 16, 2), 256, 0, stream>>>(
        F1, W2T, nullptr, f2Part, nullptr, nullptr,
        2048, NDFF, NDFF, ND,
        0, 0, 1, 0, 0, 1,
        0, 2, (long)BSROWS * ND, 0);

    // FFN2 reduce + fused loss finalize
    ffn2_reduce<<<1024, 256, 0, stream>>>(f2Part, b2, out,
                                          loss_part, hist, sep_p, out_loss);
}